// Round 6
// baseline (1459.814 us; speedup 1.0000x reference)
//
#include <hip/hip_runtime.h>
#include <stdint.h>
#include <stddef.h>

typedef __attribute__((ext_vector_type(8))) short bf16x8;
typedef __attribute__((ext_vector_type(4))) float f32x4;
typedef __attribute__((ext_vector_type(16))) float f32x16;
typedef unsigned short u16;
typedef unsigned int u32;
typedef unsigned long long u64;

static constexpr int S_ = 2048, B_ = 2, H_ = 2048, NH_ = 16, D_ = 128, M_ = 2048, FF_ = 8192;
static constexpr int SB_ = S_ * B_;   // 4096 rows of x
static constexpr int MB_ = M_ * B_;   // 4096 rows of mem

__device__ __forceinline__ float b2f(u16 b) {
  union { u32 u; float f; } v; v.u = ((u32)b) << 16; return v.f;
}
__device__ __forceinline__ u16 f2b(float f) {
  union { float f; u32 u; } v; v.f = f;
  u32 u = v.u;
  return (u16)((u + 0x7FFFu + ((u >> 16) & 1u)) >> 16);
}
__device__ __forceinline__ float geluf(float x) {
  float x3 = x * x * x;
  return 0.5f * x * (1.0f + tanhf(0.7978845608028654f * (x + 0.044715f * x3)));
}

#define LDSP(p) (reinterpret_cast<__attribute__((address_space(3))) uint32_t*>(reinterpret_cast<uintptr_t>(p)))
#define GLBP(p) (reinterpret_cast<const __attribute__((address_space(1))) uint32_t*>(reinterpret_cast<uintptr_t>(p)))

// ---------------------------------------------------------------- detectors
// flags[0]: 1 = inputs are f32, 0 = inputs are bf16
// flags[1]: mask kind: 0=uint8 bool, 1=int32, 2=bf16, 3=f32
__global__ void detect_kinds(const u32* __restrict__ x0, const u32* __restrict__ mask, int* __restrict__ flags) {
  if (threadIdx.x == 0 && blockIdx.x == 0) {
    int cnt = 0;
    for (int i = 0; i < 256; ++i) {
      u32 e = (x0[i] >> 7) & 0xFFu;   // exponent field if low halfword is a bf16
      if (e >= 118u && e <= 130u) ++cnt;
    }
    flags[0] = (cnt >= 128) ? 0 : 1;
    int all01 = 1, allf = 1, allb = 1;
    for (int i = 0; i < 256; ++i) {
      u32 v = mask[i];
      if (v > 1u) all01 = 0;
      if (v != 0u && v != 0x3F800000u) allf = 0;
      u32 lo = v & 0xFFFFu, hi = v >> 16;
      if ((lo != 0u && lo != 0x3F80u) || (hi != 0u && hi != 0x3F80u)) allb = 0;
    }
    flags[1] = all01 ? 1 : (allf ? 3 : (allb ? 2 : 0));
  }
}

// mask -> packed bitmask: bit m of word (i>>6) = 1 iff UNMASKED (keep)
__global__ void mask_bits(const void* __restrict__ mraw, const int* __restrict__ flags, u64* __restrict__ bm) {
  int i = blockIdx.x * 256 + threadIdx.x;
  int kind = flags[1];
  int masked;
  if (kind == 1)      masked = ((const int*)mraw)[i] != 0;
  else if (kind == 3) masked = ((const float*)mraw)[i] != 0.0f;
  else if (kind == 2) masked = ((const u16*)mraw)[i] != 0;
  else                masked = ((const unsigned char*)mraw)[i] != 0;
  u64 vote = __ballot(masked == 0);
  if ((threadIdx.x & 63) == 0) bm[i >> 6] = vote;
}

__global__ void cvt_f32(const void* __restrict__ src, const int* __restrict__ flags, float* __restrict__ dst, int n) {
  int i = blockIdx.x * 256 + threadIdx.x;
  if (i < n) dst[i] = flags[0] ? ((const float*)src)[i] : b2f(((const u16*)src)[i]);
}

__global__ void cast_in_bf16(const void* __restrict__ src, const int* __restrict__ flags, u16* __restrict__ dst, int n8) {
  int i = blockIdx.x * 256 + threadIdx.x;
  if (i >= n8) return;
  if (flags[0]) {
    const float4* p = (const float4*)src;
    float4 a = p[i * 2], c = p[i * 2 + 1];
    bf16x8 o;
    o[0] = (short)f2b(a.x); o[1] = (short)f2b(a.y); o[2] = (short)f2b(a.z); o[3] = (short)f2b(a.w);
    o[4] = (short)f2b(c.x); o[5] = (short)f2b(c.y); o[6] = (short)f2b(c.z); o[7] = (short)f2b(c.w);
    *(bf16x8*)&dst[i * 8] = o;
  } else {
    *(bf16x8*)&dst[i * 8] = ((const bf16x8*)src)[i];
  }
}

// ------------------------------------------------------------ transpose+cast
// in [R][C] (f32 or bf16 per flag) -> out [C][R] bf16.  grid (C/64, R/64), 256 thr.
__global__ __launch_bounds__(256) void transpose_cast(const void* __restrict__ in, const int* __restrict__ flags,
                                                      u16* __restrict__ out, int R, int C) {
  __shared__ u16 tile[64][65];
  const int isf = flags[0];
  const int tr = blockIdx.y * 64, tc = blockIdx.x * 64;
  const int tx = threadIdx.x & 63, ty = threadIdx.x >> 6;
  const float* inf = (const float*)in;
  const u16* inb = (const u16*)in;
#pragma unroll
  for (int i = 0; i < 16; ++i) {
    int r = ty * 16 + i;
    size_t idx = (size_t)(tr + r) * C + tc + tx;
    tile[r][tx] = isf ? f2b(inf[idx]) : inb[idx];
  }
  __syncthreads();
#pragma unroll
  for (int i = 0; i < 16; ++i) {
    int c = ty * 16 + i;
    out[(size_t)(tc + c) * R + tr + tx] = tile[tx][c];
  }
}

// ---------------------------------------------------------------- layernorm
template <int EXT>
__global__ __launch_bounds__(256) void layernorm_k(const void* __restrict__ xin, const int* __restrict__ flags,
                                                   const float* __restrict__ g, const float* __restrict__ bta,
                                                   u16* __restrict__ out) {
  const int row = blockIdx.x, t = threadIdx.x;
  float v[8];
  bool bfmode = EXT && (flags[0] == 0);
  if (bfmode) {
    const u16* xr = (const u16*)xin + (size_t)row * H_ + t * 8;
    bf16x8 a = *(const bf16x8*)xr;
#pragma unroll
    for (int j = 0; j < 8; ++j) v[j] = b2f((u16)a[j]);
  } else {
    const float* xr = (const float*)xin + (size_t)row * H_ + t * 8;
    float4 a = *(const float4*)xr, c = *(const float4*)(xr + 4);
    v[0] = a.x; v[1] = a.y; v[2] = a.z; v[3] = a.w;
    v[4] = c.x; v[5] = c.y; v[6] = c.z; v[7] = c.w;
  }
  float s1 = 0.f, s2 = 0.f;
#pragma unroll
  for (int j = 0; j < 8; ++j) { s1 += v[j]; s2 += v[j] * v[j]; }
#pragma unroll
  for (int off = 32; off > 0; off >>= 1) { s1 += __shfl_down(s1, off); s2 += __shfl_down(s2, off); }
  __shared__ float red[8];
  const int w = t >> 6;
  if ((t & 63) == 0) { red[w] = s1; red[4 + w] = s2; }
  __syncthreads();
  s1 = red[0] + red[1] + red[2] + red[3];
  s2 = red[4] + red[5] + red[6] + red[7];
  const float mean = s1 * (1.0f / H_);
  const float rstd = rsqrtf(s2 * (1.0f / H_) - mean * mean + 1e-5f);
  bf16x8 o;
#pragma unroll
  for (int j = 0; j < 8; ++j) {
    float y = (v[j] - mean) * rstd * g[t * 8 + j] + bta[t * 8 + j];
    o[j] = (short)f2b(y);
  }
  *(bf16x8*)(out + (size_t)row * H_ + t * 8) = o;
}

// ------------------------------------------------------------------- GEMM
// 128x128 tile, 256 threads = 4 waves (2Mx2N), per-wave 64x64 via 2x2 of
// mfma_f32_32x32x16_bf16.  BK=32, 3-slot ring, counted vmcnt(4) (never 0 in
// steady state), ONE barrier per slice, 48KB LDS -> 3 blocks/CU.
// Super-row packed LDS with XOR-chunk swizzle, linear gload_lds dest +
// inverse-permuted global source (rule #21).  2D XCD chunking.
template <int GELU, int RES, int WF, int WB, int ODYN>
__global__ __launch_bounds__(256, 3) void gemm32(const u16* __restrict__ A, const u16* __restrict__ Bt,
                                                 const float* __restrict__ bias, const float* __restrict__ res,
                                                 void* __restrict__ outF, u16* __restrict__ outB,
                                                 const int* __restrict__ flags, int Mr, int N, int K) {
  __shared__ u16 lds[3 * 8192];   // 48 KiB: 3 slots x (A 8KB + B 8KB)
  const int t = threadIdx.x;
  const int w = t >> 6, l = t & 63, lm = l & 31, lh = l >> 5;
  const int wr = w >> 1, wc = w & 1;   // 2x2 waves, per-wave 64x64
  // ---- 2D XCD-chunked block mapping
  const int gx = gridDim.x, gy = gridDim.y;
  const int orig = blockIdx.y * gx + blockIdx.x;
  const int nwg = gx * gy, per = nwg >> 3;
  int tm, tn;
  if ((gx & 7) == 0 && (per & 7) == 0) {
    const int xcd = orig & 7, p = orig >> 3;
    const int ncx = gx >> 3, cy = per >> 3;
    const int ccol = xcd % ncx, crow = xcd / ncx;
    const int px = p & 7, py = p >> 3;
    tn = (ccol * 8 + px) * 128;
    tm = (crow * cy + py) * 128;
  } else {
    tn = (orig % gx) * 128;
    tm = (orig / gx) * 128;
  }
  // ---- staging source offsets (u16 units), 2 rounds per operand
  u32 aofs[2], bofs[2];
#pragma unroll
  for (int i = 0; i < 2; ++i) {
    int idx = i * 256 + t;
    int srow = idx >> 3, p4 = idx & 7;
    int p = p4 ^ (srow & 7);
    int row = (srow << 1) | (p >> 2), ckk = p & 3;
    aofs[i] = (u32)(tm + row) * (u32)K + ckk * 8;
    bofs[i] = (u32)(tn + row) * (u32)K + ckk * 8;
  }
  const int wb8 = w * 512;   // wave-uniform LDS dest base (u16) within a 2048-u16 round
  // ---- ds_read offsets (u16): srow = packed row>>1, p = ((row&1)<<2)|(kk<<1)|lh
  int offA[2][2], offB[2][2];
#pragma unroll
  for (int mi = 0; mi < 2; ++mi)
#pragma unroll
    for (int kk = 0; kk < 2; ++kk) {
      const int p = ((lm & 1) << 2) | (kk << 1) | lh;
      const int sa = wr * 32 + mi * 16 + (lm >> 1);
      offA[mi][kk] = sa * 64 + (p ^ (sa & 7)) * 8;
      const int sb = wc * 32 + mi * 16 + (lm >> 1);
      offB[mi][kk] = sb * 64 + (p ^ (sb & 7)) * 8;
    }
  const int NS = K >> 5;
  f32x16 acc[2][2] = {};

#define STG(Pd, sl) do {                                                                              \
    u16* Ad = (Pd);                                                                                   \
    u16* Bd = (Pd) + 4096;                                                                            \
    const u32 ko = (u32)(sl) * 32;                                                                    \
    _Pragma("unroll")                                                                                 \
    for (int i = 0; i < 2; ++i) {                                                                     \
      __builtin_amdgcn_global_load_lds(GLBP(A + aofs[i] + ko), LDSP(Ad + i * 2048 + wb8), 16, 0, 0);  \
      __builtin_amdgcn_global_load_lds(GLBP(Bt + bofs[i] + ko), LDSP(Bd + i * 2048 + wb8), 16, 0, 0); \
    }                                                                                                 \
  } while (0)

  u16 *ps0 = lds, *ps1 = lds + 8192, *ps2 = lds + 16384;
  STG(ps0, 0);
  STG(ps1, 1);

  for (int s = 0; s < NS; ++s) {
    // counted wait: current slot's 4 loads done; next slot's may stay in flight
    if (s + 1 < NS) asm volatile("s_waitcnt vmcnt(4)" ::: "memory");
    else            asm volatile("s_waitcnt vmcnt(0)" ::: "memory");
    __builtin_amdgcn_s_barrier();
    if (s + 2 < NS) STG(ps2, s + 2);   // writes slot read 2 iters ago: safe post-barrier
    const u16* As = ps0;
    const u16* Bs = ps0 + 4096;
    bf16x8 af[2][2], bq[2][2];
#pragma unroll
    for (int mi = 0; mi < 2; ++mi)
#pragma unroll
      for (int kk = 0; kk < 2; ++kk) {
        af[mi][kk] = *(const bf16x8*)(As + offA[mi][kk]);
        bq[mi][kk] = *(const bf16x8*)(Bs + offB[mi][kk]);
      }
    asm volatile("s_waitcnt lgkmcnt(0)" ::: "memory");
    __builtin_amdgcn_sched_barrier(0);
    __builtin_amdgcn_s_setprio(1);
#pragma unroll
    for (int kk = 0; kk < 2; ++kk)
#pragma unroll
      for (int mi = 0; mi < 2; ++mi)
#pragma unroll
        for (int ni = 0; ni < 2; ++ni)
          acc[mi][ni] = __builtin_amdgcn_mfma_f32_32x32x16_bf16(af[mi][kk], bq[ni][kk], acc[mi][ni], 0, 0, 0);
    __builtin_amdgcn_s_setprio(0);
    __builtin_amdgcn_sched_barrier(0);
    u16* tt = ps0; ps0 = ps1; ps1 = ps2; ps2 = tt;
  }
#undef STG

  const int obf = ODYN ? (flags[0] ? 0 : 1) : 0;
#pragma unroll
  for (int mi = 0; mi < 2; ++mi) {
#pragma unroll
    for (int ni = 0; ni < 2; ++ni) {
      const int col = tn + wc * 64 + ni * 32 + lm;
      const float bv = bias[col];
#pragma unroll
      for (int r = 0; r < 16; ++r) {
        const int rw = tm + wr * 64 + mi * 32 + (r & 3) + 8 * (r >> 2) + 4 * lh;
        float vv = acc[mi][ni][r] + bv;
        if (RES) vv += res[(size_t)rw * N + col];
        if (GELU) vv = geluf(vv);
        if (WF) {
          if (ODYN && obf) ((u16*)outF)[(size_t)rw * N + col] = f2b(vv);
          else ((float*)outF)[(size_t)rw * N + col] = vv;
        }
        if (WB) outB[(size_t)rw * N + col] = f2b(vv);
      }
    }
  }
}

// --------------------------------------------------------------- l2 norms
__global__ __launch_bounds__(256) void l2_q(const float* __restrict__ qpre, u16* __restrict__ Q) {
  const int t = threadIdx.x;
  const int g = blockIdx.x * 64 + (t >> 2);
  const int lg = t & 3;
  const int h = g & (NH_ - 1), sb = g >> 4;
  const float* p = qpre + (size_t)sb * H_ + h * D_ + lg * 32;
  float vv[32];
  float ss = 0.f;
#pragma unroll
  for (int i = 0; i < 8; ++i) {
    float4 a = *(const float4*)&p[i * 4];
    vv[i * 4 + 0] = a.x; vv[i * 4 + 1] = a.y; vv[i * 4 + 2] = a.z; vv[i * 4 + 3] = a.w;
    ss += a.x * a.x + a.y * a.y + a.z * a.z + a.w * a.w;
  }
  ss += __shfl_xor(ss, 1); ss += __shfl_xor(ss, 2);
  const float sc = rsqrtf(ss + 1e-12f);
  const int s = sb >> 1, b = sb & 1;
  u16* o = Q + ((size_t)(b * NH_ + h) * S_ + s) * D_ + lg * 32;
#pragma unroll
  for (int i = 0; i < 4; ++i) {
    bf16x8 ov;
#pragma unroll
    for (int j = 0; j < 8; ++j) ov[j] = (short)f2b(vv[i * 8 + j] * sc);
    *(bf16x8*)&o[i * 8] = ov;
  }
}

__global__ __launch_bounds__(256) void l2_kv(const float* __restrict__ kvpre, u16* __restrict__ Kq, u16* __restrict__ Vt) {
  __shared__ u16 vtT[128][72];
  const int t = threadIdx.x;
  const int bid = blockIdx.x;
  const int mt = bid & 31, h = (bid >> 5) & 15, b = bid >> 9;
  const int lm = t >> 2, lg = t & 3;
  const int m = mt * 64 + lm;
  const size_t rowoff = (size_t)(m * B_ + b) * (2 * H_) + h * 256;
  float vv[32];
  { // K half
    const float* p = kvpre + rowoff + lg * 32;
    float ss = 0.f;
#pragma unroll
    for (int i = 0; i < 8; ++i) {
      float4 a = *(const float4*)&p[i * 4];
      vv[i * 4 + 0] = a.x; vv[i * 4 + 1] = a.y; vv[i * 4 + 2] = a.z; vv[i * 4 + 3] = a.w;
      ss += a.x * a.x + a.y * a.y + a.z * a.z + a.w * a.w;
    }
    ss += __shfl_xor(ss, 1); ss += __shfl_xor(ss, 2);
    const float sc = rsqrtf(ss + 1e-12f);
    u16* o = Kq + ((size_t)(b * NH_ + h) * M_ + m) * D_ + lg * 32;
#pragma unroll
    for (int i = 0; i < 4; ++i) {
      bf16x8 ov;
#pragma unroll
      for (int j = 0; j < 8; ++j) ov[j] = (short)f2b(vv[i * 8 + j] * sc);
      *(bf16x8*)&o[i * 8] = ov;
    }
  }
  { // V half -> LDS transposed
    const float* p = kvpre + rowoff + 128 + lg * 32;
    float ss = 0.f;
#pragma unroll
    for (int i = 0; i < 8; ++i) {
      float4 a = *(const float4*)&p[i * 4];
      vv[i * 4 + 0] = a.x; vv[i * 4 + 1] = a.y; vv[i * 4 + 2] = a.z; vv[i * 4 + 3] = a.w;
      ss += a.x * a.x + a.y * a.y + a.z * a.z + a.w * a.w;
    }
    ss += __shfl_xor(ss, 1); ss += __shfl_xor(ss, 2);
    const float sc = rsqrtf(ss + 1e-12f);
#pragma unroll
    for (int i = 0; i < 32; ++i) vtT[lg * 32 + i][lm] = f2b(vv[i] * sc);
  }
  __syncthreads();
  const int d = t >> 1, half = t & 1;
  u16* o = Vt + ((size_t)(b * NH_ + h) * D_ + d) * M_ + mt * 64 + half * 32;
#pragma unroll
  for (int i = 0; i < 4; ++i) {
    bf16x8 ov = *(const bf16x8*)&vtT[d][half * 32 + i * 8];
    *(bf16x8*)&o[i * 8] = ov;
  }
}

// -------------------------------------------------------------- attention
// Barrier-free: 1 wave per block, 32 q-rows/wave.  K/V read directly from
// global (L2-resident per bh after XCD grouping); mask via packed bitmask
// (L2-resident 1MB); only wave-local P goes through LDS (no __syncthreads
// anywhere).  Grid 2048 blocks; XCD-grouped: 4 bh per XCD.
__global__ __launch_bounds__(64, 2) void attn_k(const u16* __restrict__ Q, const u16* __restrict__ Kq,
                                                const u16* __restrict__ Vt, const u64* __restrict__ BM,
                                                u16* __restrict__ ctx) {
  __shared__ u16 Pl[32 * 72];
  const int l = threadIdx.x, lr = l & 15, lk = l >> 4;
  const int lin = blockIdx.x;
  const int xcd = lin & 7, idx = lin >> 3;        // idx 0..255
  const int bh = xcd * 4 + (idx >> 6);            // 4 bh per XCD
  const int sbase = (idx & 63) * 32;
  const int b = bh >> 4, h = bh & 15;
  const u16* Qb = Q + ((size_t)bh * S_ + sbase) * D_;
  bf16x8 qf[2][4];
#pragma unroll
  for (int sf = 0; sf < 2; ++sf)
#pragma unroll
    for (int kc = 0; kc < 4; ++kc)
      qf[sf][kc] = *(const bf16x8*)&Qb[(sf * 16 + lr) * D_ + kc * 32 + lk * 8];
  f32x4 oacc[2][8] = {};
  float den[2][4] = {};
  const u16* Kb = Kq + (size_t)bh * M_ * D_;
  const u16* Vb = Vt + (size_t)bh * D_ * M_;
  const u64* Mb = BM + ((size_t)b * S_ + sbase) * (M_ / 64);
  const float invn = 0.08838834764831845f;  // 1/sqrt(128)

  for (int m0 = 0; m0 < M_; m0 += 64) {
    // ---- QK^T: K frags direct from global (L2 hit)
    f32x4 sc[2][4] = {};
#pragma unroll
    for (int mf = 0; mf < 4; ++mf) {
#pragma unroll
      for (int kc = 0; kc < 4; ++kc) {
        bf16x8 kf = *(const bf16x8*)&Kb[(size_t)(m0 + mf * 16 + lr) * D_ + kc * 32 + lk * 8];
#pragma unroll
        for (int sf = 0; sf < 2; ++sf)
          sc[sf][mf] = __builtin_amdgcn_mfma_f32_16x16x32_bf16(qf[sf][kc], kf, sc[sf][mf], 0, 0, 0);
      }
    }
    // ---- mask (bitmask) + exp + P write (wave-local LDS)
    const int mw = m0 >> 6;
#pragma unroll
    for (int sf = 0; sf < 2; ++sf)
#pragma unroll
      for (int j2 = 0; j2 < 4; ++j2) {
        const int rloc = sf * 16 + lk * 4 + j2;
        const u64 wbits = Mb[(size_t)rloc * (M_ / 64) + mw];
#pragma unroll
        for (int mf = 0; mf < 4; ++mf) {
          float p = __expf(sc[sf][mf][j2] * invn);
          p = ((wbits >> (mf * 16 + lr)) & 1ull) ? p : 0.0f;
          den[sf][j2] += p;
          Pl[rloc * 72 + mf * 16 + lr] = f2b(p);
        }
      }
    asm volatile("s_waitcnt lgkmcnt(0)" ::: "memory");
    __builtin_amdgcn_sched_barrier(0);
    // ---- PV: V frags direct from global (L2 hit)
#pragma unroll
    for (int kc2 = 0; kc2 < 2; ++kc2) {
      bf16x8 pa[2];
#pragma unroll
      for (int sf = 0; sf < 2; ++sf)
        pa[sf] = *(const bf16x8*)&Pl[(sf * 16 + lr) * 72 + kc2 * 32 + lk * 8];
#pragma unroll
      for (int nf = 0; nf < 8; ++nf) {
        bf16x8 vf = *(const bf16x8*)&Vb[(size_t)(nf * 16 + lr) * M_ + m0 + (kc2 * 4 + lk) * 8];
#pragma unroll
        for (int sf = 0; sf < 2; ++sf)
          oacc[sf][nf] = __builtin_amdgcn_mfma_f32_16x16x32_bf16(pa[sf], vf, oacc[sf][nf], 0, 0, 0);
      }
    }
  }
#pragma unroll
  for (int sf = 0; sf < 2; ++sf)
#pragma unroll
    for (int j2 = 0; j2 < 4; ++j2) {
      float d = den[sf][j2];
      d += __shfl_xor(d, 1); d += __shfl_xor(d, 2); d += __shfl_xor(d, 4); d += __shfl_xor(d, 8);
      den[sf][j2] = 1.0f / fmaxf(d, 1e-20f);
    }
#pragma unroll
  for (int sf = 0; sf < 2; ++sf)
#pragma unroll
    for (int nf = 0; nf < 8; ++nf)
#pragma unroll
      for (int j2 = 0; j2 < 4; ++j2) {
        int s = sbase + sf * 16 + lk * 4 + j2;
        int dd = nf * 16 + lr;
        ctx[((size_t)s * B_ + b) * H_ + h * D_ + dd] = f2b(oacc[sf][nf][j2] * den[sf][j2]);
      }
}

// ------------------------------------------------------------------- host
extern "C" void kernel_launch(void* const* d_in, const int* in_sizes, int n_in,
                              void* d_out, int out_size, void* d_ws, size_t ws_size,
                              hipStream_t stream) {
  (void)in_sizes; (void)n_in; (void)out_size; (void)ws_size;
  char* ws = (char*)d_ws;
  u16* WT     = (u16*)(ws + 0);            // 33.55 MB  transposed bf16 weights (reused)
  void* MID   = (void*)(ws + 33554432);    // 67.11 MB  mlp mid bf16 / q_pre f32 / kv_pre f32
  float* XF   = (float*)(ws + 100663296);  // 33.55 MB  running x (f32)
  u16* HB     = (u16*)(ws + 134217728);    // 16.78 MB  LN outputs bf16
  u16* MEMB   = (u16*)(ws + 150994944);    // 16.78 MB  mem bf16, later ctx bf16
  u16* QB     = (u16*)(ws + 167772160);    // 16.78 MB  Q [B][NH][S][D]
  u16* KB     = (u16*)(ws + 184549376);    // 16.78 MB  K [B][NH][M][D]
  u16* VTB    = (u16*)(ws + 201326592);    // 16.78 MB  V^T [B][NH][D][M]
  u64* BMB    = (u64*)(ws + 218103808);    // 1.05 MB   packed mask bitmask
  float* SM   = (float*)(ws + 234881024);  // small f32 arrays
  int* FLAGS  = (int*)(ws + 235044864);

  float* Bias1  = SM + 0;      // b_mlp1_in  8192
  float* Bias1o = SM + 8192;   // b_mlp1_out 2048
  float* BiasQ  = SM + 10240;  // b_q        2048
  float* BiasKV = SM + 12288;  // b_kv       4096
  float* BiasD  = SM + 16384;  // b_dense    2048
  float* Bias2  = SM + 18432;  // b_mlp2_in  8192
  float* Bias2o = SM + 26624;  // b_mlp2_out 2048
  float* G1v = SM + 28672; float* B1v = SM + 30720;
  float* G2v = SM + 32768; float* B2v = SM + 34816;
  float* G3v = SM + 36864; float* B3v = SM + 38912;

  detect_kinds<<<1, 64, 0, stream>>>((const u32*)d_in[0], (const u32*)d_in[2], FLAGS);

  cvt_f32<<<32, 256, 0, stream>>>(d_in[10], FLAGS, Bias1, 8192);
  cvt_f32<<<8, 256, 0, stream>>>(d_in[12], FLAGS, Bias1o, 2048);
  cvt_f32<<<8, 256, 0, stream>>>(d_in[14], FLAGS, BiasQ, 2048);
  cvt_f32<<<16, 256, 0, stream>>>(d_in[16], FLAGS, BiasKV, 4096);
  cvt_f32<<<8, 256, 0, stream>>>(d_in[18], FLAGS, BiasD, 2048);
  cvt_f32<<<32, 256, 0, stream>>>(d_in[20], FLAGS, Bias2, 8192);
  cvt_f32<<<8, 256, 0, stream>>>(d_in[22], FLAGS, Bias2o, 2048);
  cvt_f32<<<8, 256, 0, stream>>>(d_in[3], FLAGS, G1v, 2048);
  cvt_f32<<<8, 256, 0, stream>>>(d_in[4], FLAGS, B1v, 2048);
  cvt_f32<<<8, 256, 0, stream>>>(d_in[5], FLAGS, G2v, 2048);
  cvt_f32<<<8, 256, 0, stream>>>(d_in[6], FLAGS, B2v, 2048);
  cvt_f32<<<8, 256, 0, stream>>>(d_in[7], FLAGS, G3v, 2048);
  cvt_f32<<<8, 256, 0, stream>>>(d_in[8], FLAGS, B3v, 2048);

  mask_bits<<<(B_ * S_ * M_) / 256, 256, 0, stream>>>(d_in[2], FLAGS, BMB);
  cast_in_bf16<<<(MB_ * H_ / 8) / 256, 256, 0, stream>>>(d_in[1], FLAGS, MEMB, MB_ * H_ / 8);

  dim3 blk(256);
  // ---- mlp1: x = mlp(ln1(x))  (no residual)
  layernorm_k<1><<<SB_, blk, 0, stream>>>(d_in[0], FLAGS, G1v, B1v, HB);
  transpose_cast<<<dim3(FF_ / 64, H_ / 64), blk, 0, stream>>>(d_in[9], FLAGS, WT, H_, FF_);
  gemm32<1, 0, 0, 1, 0><<<dim3(FF_ / 128, SB_ / 128), blk, 0, stream>>>(HB, WT, Bias1, nullptr, nullptr, (u16*)MID, FLAGS, SB_, FF_, H_);
  transpose_cast<<<dim3(H_ / 64, FF_ / 64), blk, 0, stream>>>(d_in[11], FLAGS, WT, FF_, H_);
  gemm32<0, 0, 1, 0, 0><<<dim3(H_ / 128, SB_ / 128), blk, 0, stream>>>((u16*)MID, WT, Bias1o, nullptr, XF, nullptr, FLAGS, SB_, H_, FF_);

  // ---- memory attention
  layernorm_k<0><<<SB_, blk, 0, stream>>>(XF, FLAGS, G2v, B2v, HB);
  transpose_cast<<<dim3(H_ / 64, H_ / 64), blk, 0, stream>>>(d_in[13], FLAGS, WT, H_, H_);
  gemm32<0, 0, 1, 0, 0><<<dim3(H_ / 128, SB_ / 128), blk, 0, stream>>>(HB, WT, BiasQ, nullptr, MID, nullptr, FLAGS, SB_, H_, H_);
  l2_q<<<(SB_ * NH_) / 64, blk, 0, stream>>>((const float*)MID, QB);
  transpose_cast<<<dim3(2 * H_ / 64, H_ / 64), blk, 0, stream>>>(d_in[15], FLAGS, WT, H_, 2 * H_);
  gemm32<0, 0, 1, 0, 0><<<dim3(2 * H_ / 128, MB_ / 128), blk, 0, stream>>>(MEMB, WT, BiasKV, nullptr, MID, nullptr, FLAGS, MB_, 2 * H_, H_);
  l2_kv<<<B_ * NH_ * (M_ / 64), blk, 0, stream>>>((const float*)MID, KB, VTB);
  attn_k<<<2048, 64, 0, stream>>>(QB, KB, VTB, BMB, MEMB);
  transpose_cast<<<dim3(H_ / 64, H_ / 64), blk, 0, stream>>>(d_in[17], FLAGS, WT, H_, H_);
  gemm32<0, 1, 1, 0, 0><<<dim3(H_ / 128, SB_ / 128), blk, 0, stream>>>(MEMB, WT, BiasD, XF, XF, nullptr, FLAGS, SB_, H_, H_);

  // ---- mlp2 with residual
  layernorm_k<0><<<SB_, blk, 0, stream>>>(XF, FLAGS, G3v, B3v, HB);
  transpose_cast<<<dim3(FF_ / 64, H_ / 64), blk, 0, stream>>>(d_in[19], FLAGS, WT, H_, FF_);
  gemm32<1, 0, 0, 1, 0><<<dim3(FF_ / 128, SB_ / 128), blk, 0, stream>>>(HB, WT, Bias2, nullptr, nullptr, (u16*)MID, FLAGS, SB_, FF_, H_);
  transpose_cast<<<dim3(H_ / 64, FF_ / 64), blk, 0, stream>>>(d_in[21], FLAGS, WT, FF_, H_);
  gemm32<0, 1, 1, 0, 1><<<dim3(H_ / 128, SB_ / 128), blk, 0, stream>>>((u16*)MID, WT, Bias2o, XF, d_out, nullptr, FLAGS, SB_, H_, FF_);
}

// Round 7
// 1413.708 us; speedup vs baseline: 1.0326x; 1.0326x over previous
//
#include <hip/hip_runtime.h>
#include <stdint.h>
#include <stddef.h>

typedef __attribute__((ext_vector_type(8))) short bf16x8;
typedef __attribute__((ext_vector_type(4))) float f32x4;
typedef unsigned short u16;
typedef unsigned int u32;
typedef unsigned long long u64;

static constexpr int S_ = 2048, B_ = 2, H_ = 2048, NH_ = 16, D_ = 128, M_ = 2048, FF_ = 8192;
static constexpr int SB_ = S_ * B_;
static constexpr int MB_ = M_ * B_;

__device__ __forceinline__ float b2f(u16 b) {
  union { u32 u; float f; } v; v.u = ((u32)b) << 16; return v.f;
}
__device__ __forceinline__ u16 f2b(float f) {
  union { float f; u32 u; } v; v.f = f;
  u32 u = v.u;
  return (u16)((u + 0x7FFFu + ((u >> 16) & 1u)) >> 16);
}
__device__ __forceinline__ float geluf(float x) {
  float x3 = x * x * x;
  return 0.5f * x * (1.0f + tanhf(0.7978845608028654f * (x + 0.044715f * x3)));
}

#define LDSP(p) (reinterpret_cast<__attribute__((address_space(3))) uint32_t*>(reinterpret_cast<uintptr_t>(p)))
#define GLBP(p) (reinterpret_cast<const __attribute__((address_space(1))) uint32_t*>(reinterpret_cast<uintptr_t>(p)))

// ---------------------------------------------------------------- detectors
__global__ void detect_kinds(const u32* __restrict__ x0, const u32* __restrict__ mask, int* __restrict__ flags) {
  if (threadIdx.x == 0 && blockIdx.x == 0) {
    int cnt = 0;
    for (int i = 0; i < 256; ++i) {
      u32 e = (x0[i] >> 7) & 0xFFu;
      if (e >= 118u && e <= 130u) ++cnt;
    }
    flags[0] = (cnt >= 128) ? 0 : 1;
    int all01 = 1, allf = 1, allb = 1;
    for (int i = 0; i < 256; ++i) {
      u32 v = mask[i];
      if (v > 1u) all01 = 0;
      if (v != 0u && v != 0x3F800000u) allf = 0;
      u32 lo = v & 0xFFFFu, hi = v >> 16;
      if ((lo != 0u && lo != 0x3F80u) || (hi != 0u && hi != 0x3F80u)) allb = 0;
    }
    flags[1] = all01 ? 1 : (allf ? 3 : (allb ? 2 : 0));
  }
}

// mask -> packed bitmask: bit m = 1 iff UNMASKED
__global__ void mask_bits(const void* __restrict__ mraw, const int* __restrict__ flags, u64* __restrict__ bm) {
  int i = blockIdx.x * 256 + threadIdx.x;
  int kind = flags[1];
  int masked;
  if (kind == 1)      masked = ((const int*)mraw)[i] != 0;
  else if (kind == 3) masked = ((const float*)mraw)[i] != 0.0f;
  else if (kind == 2) masked = ((const u16*)mraw)[i] != 0;
  else                masked = ((const unsigned char*)mraw)[i] != 0;
  u64 vote = __ballot(masked == 0);
  if ((threadIdx.x & 63) == 0) bm[i >> 6] = vote;
}

__global__ void cvt_f32(const void* __restrict__ src, const int* __restrict__ flags, float* __restrict__ dst, int n) {
  int i = blockIdx.x * 256 + threadIdx.x;
  if (i < n) dst[i] = flags[0] ? ((const float*)src)[i] : b2f(((const u16*)src)[i]);
}

__global__ void cast_in_bf16(const void* __restrict__ src, const int* __restrict__ flags, u16* __restrict__ dst, int n8) {
  int i = blockIdx.x * 256 + threadIdx.x;
  if (i >= n8) return;
  if (flags[0]) {
    const float4* p = (const float4*)src;
    float4 a = p[i * 2], c = p[i * 2 + 1];
    bf16x8 o;
    o[0] = (short)f2b(a.x); o[1] = (short)f2b(a.y); o[2] = (short)f2b(a.z); o[3] = (short)f2b(a.w);
    o[4] = (short)f2b(c.x); o[5] = (short)f2b(c.y); o[6] = (short)f2b(c.z); o[7] = (short)f2b(c.w);
    *(bf16x8*)&dst[i * 8] = o;
  } else {
    *(bf16x8*)&dst[i * 8] = ((const bf16x8*)src)[i];
  }
}

// ------------------------------------------------------------ transpose+cast
__global__ __launch_bounds__(256) void transpose_cast(const void* __restrict__ in, const int* __restrict__ flags,
                                                      u16* __restrict__ out, int R, int C) {
  __shared__ u16 tile[64][65];
  const int isf = flags[0];
  const int tr = blockIdx.y * 64, tc = blockIdx.x * 64;
  const int tx = threadIdx.x & 63, ty = threadIdx.x >> 6;
  const float* inf = (const float*)in;
  const u16* inb = (const u16*)in;
#pragma unroll
  for (int i = 0; i < 16; ++i) {
    int r = ty * 16 + i;
    size_t idx = (size_t)(tr + r) * C + tc + tx;
    tile[r][tx] = isf ? f2b(inf[idx]) : inb[idx];
  }
  __syncthreads();
#pragma unroll
  for (int i = 0; i < 16; ++i) {
    int c = ty * 16 + i;
    out[(size_t)(tc + c) * R + tr + tx] = tile[tx][c];
  }
}

// ---------------------------------------------------------------- layernorm
template <int EXT>
__global__ __launch_bounds__(256) void layernorm_k(const void* __restrict__ xin, const int* __restrict__ flags,
                                                   const float* __restrict__ g, const float* __restrict__ bta,
                                                   u16* __restrict__ out) {
  const int row = blockIdx.x, t = threadIdx.x;
  float v[8];
  bool bfmode = EXT && (flags[0] == 0);
  if (bfmode) {
    const u16* xr = (const u16*)xin + (size_t)row * H_ + t * 8;
    bf16x8 a = *(const bf16x8*)xr;
#pragma unroll
    for (int j = 0; j < 8; ++j) v[j] = b2f((u16)a[j]);
  } else {
    const float* xr = (const float*)xin + (size_t)row * H_ + t * 8;
    float4 a = *(const float4*)xr, c = *(const float4*)(xr + 4);
    v[0] = a.x; v[1] = a.y; v[2] = a.z; v[3] = a.w;
    v[4] = c.x; v[5] = c.y; v[6] = c.z; v[7] = c.w;
  }
  float s1 = 0.f, s2 = 0.f;
#pragma unroll
  for (int j = 0; j < 8; ++j) { s1 += v[j]; s2 += v[j] * v[j]; }
#pragma unroll
  for (int off = 32; off > 0; off >>= 1) { s1 += __shfl_down(s1, off); s2 += __shfl_down(s2, off); }
  __shared__ float red[8];
  const int w = t >> 6;
  if ((t & 63) == 0) { red[w] = s1; red[4 + w] = s2; }
  __syncthreads();
  s1 = red[0] + red[1] + red[2] + red[3];
  s2 = red[4] + red[5] + red[6] + red[7];
  const float mean = s1 * (1.0f / H_);
  const float rstd = rsqrtf(s2 * (1.0f / H_) - mean * mean + 1e-5f);
  bf16x8 o;
#pragma unroll
  for (int j = 0; j < 8; ++j) {
    float y = (v[j] - mean) * rstd * g[t * 8 + j] + bta[t * 8 + j];
    o[j] = (short)f2b(y);
  }
  *(bf16x8*)(out + (size_t)row * H_ + t * 8) = o;
}

// ------------------------------------------------------------------- GEMM
// 8-phase 256xBN template (T2+T3+T4+T5).  512 thr = 8 waves (2M x BN/64|4N).
// BK=64 K-tiles; per K-tile 4 phases over C-quadrants (m0n0,m0n1,m1n0,m1n1);
// each phase: {ds_reads; stage 1 half-tile (2 gload_lds); bar; lgkm0; prio1;
// 16|8 MFMA; prio0; [vmcnt(4) @P4/P8]; bar}.  LDS 128KB: A ring 4x16KB,
// B ring 4x16KB.  Stage targets verified drained (see schedule proofs).
template <int BN, int GELU, int RES, int WF, int WB, int ODYN>
__global__ __launch_bounds__(512, 2) void gemm8p(const u16* __restrict__ A, const u16* __restrict__ Bt,
                                                 const float* __restrict__ bias, const float* __restrict__ res,
                                                 void* __restrict__ outF, u16* __restrict__ outB,
                                                 const int* __restrict__ flags, int Mr, int N, int K) {
  constexpr int NBF = (BN == 256) ? 2 : 1;   // B frags per n-half group
  __shared__ u16 lds[65536];                 // 128 KiB
  const int t = threadIdx.x;
  const int w = t >> 6, l = t & 63, lr = l & 15, lk = l >> 4;
  const int wr = w >> 2, wc = w & 3;
  // 2D XCD-chunked block mapping
  const int gx = gridDim.x, gy = gridDim.y;
  const int orig = blockIdx.y * gx + blockIdx.x;
  const int nwg = gx * gy, per = nwg >> 3;
  int tm, tn;
  {
    const int xcd = orig & 7, p = orig >> 3;
    const int ncx = gx >> 3 ? gx >> 3 : 1;
    if ((gx & 7) == 0 && (per & 7) == 0) {
      const int cy = per >> 3;
      const int ccol = xcd % ncx, crow = xcd / ncx;
      const int px = p & 7, py = p >> 3;
      tn = (ccol * 8 + px) * BN;
      tm = (crow * cy + py) * 256;
    } else {
      tn = (orig % gx) * BN;
      tm = (orig / gx) * 256;
    }
  }
  // staging per-thread consts
  const int r0 = t >> 3;
  const int cl = (t & 7) ^ (r0 & 7);
  const u32 abase = (u32)(tm + r0) * (u32)K + (u32)cl * 8;
  const u32 bbase = (u32)(tn + r0) * (u32)K + (u32)cl * 8;
  const int wdst = w * 512;
  // ds_read consts
  const int cso0 = ((0 + lk) ^ (lr & 7)) * 8;
  const int cso1 = ((4 + lk) ^ (lr & 7)) * 8;
  const int brow0 = (BN == 256) ? ((wc & 1) * 64) : (wc * 32);

  const int NT = K >> 6, NI = NT >> 1;
  f32x4 acc[8][2 * NBF] = {};

#define STGA_(h) do { if ((h) < 2 * NT) {                                                              \
    const int sl_ = ((h) & 3) * 8192;                                                                  \
    const u32 so_ = abase + ((u32)((h) & 1) * 128u) * (u32)K + ((u32)((h) >> 1)) * 64u;                \
    __builtin_amdgcn_global_load_lds(GLBP(A + so_), LDSP(lds + sl_ + wdst), 16, 0, 0);                 \
    __builtin_amdgcn_global_load_lds(GLBP(A + so_ + (u32)64 * (u32)K), LDSP(lds + sl_ + 4096 + wdst), 16, 0, 0); \
  } } while (0)
#define STGB_(h) do {                                                                                  \
    if constexpr (BN == 256) { if ((h) < 2 * NT) {                                                     \
      const int sl_ = 32768 + ((h) & 3) * 8192;                                                        \
      const u32 so_ = bbase + ((u32)((h) & 1) * 128u) * (u32)K + ((u32)((h) >> 1)) * 64u;              \
      __builtin_amdgcn_global_load_lds(GLBP(Bt + so_), LDSP(lds + sl_ + wdst), 16, 0, 0);              \
      __builtin_amdgcn_global_load_lds(GLBP(Bt + so_ + (u32)64 * (u32)K), LDSP(lds + sl_ + 4096 + wdst), 16, 0, 0); \
    } } else { if ((h) < NT) {                                                                         \
      const int sl_ = 32768 + ((h) & 3) * 8192;                                                        \
      const u32 so_ = bbase + ((u32)(h)) * 64u;                                                        \
      __builtin_amdgcn_global_load_lds(GLBP(Bt + so_), LDSP(lds + sl_ + wdst), 16, 0, 0);              \
      __builtin_amdgcn_global_load_lds(GLBP(Bt + so_ + (u32)64 * (u32)K), LDSP(lds + sl_ + 4096 + wdst), 16, 0, 0); \
    } }                                                                                                \
  } while (0)
#define RDA_(dst, mh, sa)                                                                              \
  _Pragma("unroll") for (int mf2 = 0; mf2 < 4; ++mf2) {                                                \
    const u16* p_ = lds + (sa) * 8192 + ((mh) * 64 + mf2 * 16 + lr) * 64;                              \
    dst[mf2][0] = *(const bf16x8*)(p_ + cso0);                                                         \
    dst[mf2][1] = *(const bf16x8*)(p_ + cso1); }
#define RDB_(dst, nh, sb)                                                                              \
  _Pragma("unroll") for (int nf2 = 0; nf2 < NBF; ++nf2) {                                              \
    const u16* p_ = lds + 32768 + (sb) * 8192 + (brow0 + ((nh) * NBF + nf2) * 16 + lr) * 64;           \
    dst[nf2][0] = *(const bf16x8*)(p_ + cso0);                                                         \
    dst[nf2][1] = *(const bf16x8*)(p_ + cso1); }
#define MM_(afX, bqX, mh, nh)                                                                          \
  _Pragma("unroll") for (int kk = 0; kk < 2; ++kk)                                                     \
  _Pragma("unroll") for (int mf2 = 0; mf2 < 4; ++mf2)                                                  \
  _Pragma("unroll") for (int nf2 = 0; nf2 < NBF; ++nf2)                                                \
    acc[(mh) * 4 + mf2][(nh) * NBF + nf2] = __builtin_amdgcn_mfma_f32_16x16x32_bf16(                   \
        afX[mf2][kk], bqX[nf2][kk], acc[(mh) * 4 + mf2][(nh) * NBF + nf2], 0, 0, 0);
#define PHASE_MID()                                                                                    \
  __builtin_amdgcn_s_barrier();                                                                        \
  asm volatile("s_waitcnt lgkmcnt(0)" ::: "memory");                                                   \
  __builtin_amdgcn_sched_barrier(0);                                                                   \
  __builtin_amdgcn_s_setprio(1);
#define PHASE_END()                                                                                    \
  __builtin_amdgcn_s_setprio(0);                                                                       \
  __builtin_amdgcn_sched_barrier(0);                                                                   \
  __builtin_amdgcn_s_barrier();

  // ---- prologue
  if constexpr (BN == 256) {
    STGB_(0); STGA_(0); STGB_(1); STGA_(1); STGB_(2); STGA_(2);
  } else {
    STGB_(0); STGA_(0); STGA_(1); STGB_(1); STGA_(2);
  }
  asm volatile("s_waitcnt vmcnt(4)" ::: "memory");
  __builtin_amdgcn_s_barrier();

  for (int it = 0; it < NI; ++it) {
    const int T0 = it * 2;
    const int saA0 = (2 * T0 + wr) & 3;
    const int saA1 = (2 * T0 + 2 + wr) & 3;
    const int sbB0 = (BN == 256) ? ((2 * T0 + (wc >> 1)) & 3) : (T0 & 3);
    const int sbB1 = (BN == 256) ? ((2 * T0 + 2 + (wc >> 1)) & 3) : ((T0 + 1) & 3);
    const bool last = (it + 1 == NI);
    bf16x8 af[4][2], bq0[NBF][2], bq1[NBF][2];

    // ======== tile T0 ========
    // P1: (m0, n0)
    RDA_(af, 0, saA0); RDB_(bq0, 0, sbB0);
    if constexpr (BN == 256) STGB_(4 * it + 3); else STGA_(4 * it + 3);
    PHASE_MID(); MM_(af, bq0, 0, 0); PHASE_END();
    // P2: (m0, n1)
    RDB_(bq1, 1, sbB0);
    if constexpr (BN == 256) STGA_(4 * it + 3);
    PHASE_MID(); MM_(af, bq1, 0, 1); PHASE_END();
    // P3: (m1, n0)
    RDA_(af, 1, saA0);
    if constexpr (BN == 256) STGB_(4 * it + 4); else STGB_(2 * it + 2);
    PHASE_MID(); MM_(af, bq0, 1, 0); PHASE_END();
    // P4: (m1, n1) + vmcnt
    STGA_(4 * it + 4);
    __builtin_amdgcn_s_barrier();
    __builtin_amdgcn_s_setprio(1);
    MM_(af, bq1, 1, 1);
    __builtin_amdgcn_s_setprio(0);
    __builtin_amdgcn_sched_barrier(0);
    if (!last) { asm volatile("s_waitcnt vmcnt(4)" ::: "memory"); }
    else       { asm volatile("s_waitcnt vmcnt(0)" ::: "memory"); }
    __builtin_amdgcn_s_barrier();

    // ======== tile T0+1 ========
    // P5
    RDA_(af, 0, saA1); RDB_(bq0, 0, sbB1);
    if constexpr (BN == 256) STGB_(4 * it + 5); else STGA_(4 * it + 5);
    PHASE_MID(); MM_(af, bq0, 0, 0); PHASE_END();
    // P6
    RDB_(bq1, 1, sbB1);
    if constexpr (BN == 256) STGA_(4 * it + 5); else STGB_(2 * it + 3);
    PHASE_MID(); MM_(af, bq1, 0, 1); PHASE_END();
    // P7
    RDA_(af, 1, saA1);
    if constexpr (BN == 256) STGB_(4 * it + 6);
    PHASE_MID(); MM_(af, bq0, 1, 0); PHASE_END();
    // P8 + vmcnt
    STGA_(4 * it + 6);
    __builtin_amdgcn_s_barrier();
    __builtin_amdgcn_s_setprio(1);
    MM_(af, bq1, 1, 1);
    __builtin_amdgcn_s_setprio(0);
    __builtin_amdgcn_sched_barrier(0);
    if (!last) { asm volatile("s_waitcnt vmcnt(4)" ::: "memory"); }
    __builtin_amdgcn_s_barrier();
  }
#undef STGA_
#undef STGB_
#undef RDA_
#undef RDB_
#undef MM_
#undef PHASE_MID
#undef PHASE_END

  const int obf = ODYN ? (flags[0] ? 0 : 1) : 0;
  (void)Mr;
#pragma unroll
  for (int mf = 0; mf < 8; ++mf) {
#pragma unroll
    for (int nf = 0; nf < 2 * NBF; ++nf) {
      const int col = tn + wc * (BN == 256 ? 64 : 32) + nf * 16 + lr;
      const float bv = bias[col];
#pragma unroll
      for (int j = 0; j < 4; ++j) {
        const int rw = tm + wr * 128 + mf * 16 + lk * 4 + j;
        float vv = acc[mf][nf][j] + bv;
        if (RES) vv += res[(size_t)rw * N + col];
        if (GELU) vv = geluf(vv);
        if (WF) {
          if (ODYN && obf) ((u16*)outF)[(size_t)rw * N + col] = f2b(vv);
          else ((float*)outF)[(size_t)rw * N + col] = vv;
        }
        if (WB) outB[(size_t)rw * N + col] = f2b(vv);
      }
    }
  }
}

// --------------------------------------------------------------- l2 norms
__global__ __launch_bounds__(256) void l2_q(const float* __restrict__ qpre, u16* __restrict__ Q) {
  const int t = threadIdx.x;
  const int g = blockIdx.x * 64 + (t >> 2);
  const int lg = t & 3;
  const int h = g & (NH_ - 1), sb = g >> 4;
  const float* p = qpre + (size_t)sb * H_ + h * D_ + lg * 32;
  float vv[32];
  float ss = 0.f;
#pragma unroll
  for (int i = 0; i < 8; ++i) {
    float4 a = *(const float4*)&p[i * 4];
    vv[i * 4 + 0] = a.x; vv[i * 4 + 1] = a.y; vv[i * 4 + 2] = a.z; vv[i * 4 + 3] = a.w;
    ss += a.x * a.x + a.y * a.y + a.z * a.z + a.w * a.w;
  }
  ss += __shfl_xor(ss, 1); ss += __shfl_xor(ss, 2);
  const float sc = rsqrtf(ss + 1e-12f);
  const int s = sb >> 1, b = sb & 1;
  u16* o = Q + ((size_t)(b * NH_ + h) * S_ + s) * D_ + lg * 32;
#pragma unroll
  for (int i = 0; i < 4; ++i) {
    bf16x8 ov;
#pragma unroll
    for (int j = 0; j < 8; ++j) ov[j] = (short)f2b(vv[i * 8 + j] * sc);
    *(bf16x8*)&o[i * 8] = ov;
  }
}

__global__ __launch_bounds__(256) void l2_kv(const float* __restrict__ kvpre, u16* __restrict__ Kq, u16* __restrict__ Vt) {
  __shared__ u16 vtT[128][72];
  const int t = threadIdx.x;
  const int bid = blockIdx.x;
  const int mt = bid & 31, h = (bid >> 5) & 15, b = bid >> 9;
  const int lm = t >> 2, lg = t & 3;
  const int m = mt * 64 + lm;
  const size_t rowoff = (size_t)(m * B_ + b) * (2 * H_) + h * 256;
  float vv[32];
  { // K half
    const float* p = kvpre + rowoff + lg * 32;
    float ss = 0.f;
#pragma unroll
    for (int i = 0; i < 8; ++i) {
      float4 a = *(const float4*)&p[i * 4];
      vv[i * 4 + 0] = a.x; vv[i * 4 + 1] = a.y; vv[i * 4 + 2] = a.z; vv[i * 4 + 3] = a.w;
      ss += a.x * a.x + a.y * a.y + a.z * a.z + a.w * a.w;
    }
    ss += __shfl_xor(ss, 1); ss += __shfl_xor(ss, 2);
    const float sc = rsqrtf(ss + 1e-12f);
    u16* o = Kq + ((size_t)(b * NH_ + h) * M_ + m) * D_ + lg * 32;
#pragma unroll
    for (int i = 0; i < 4; ++i) {
      bf16x8 ov;
#pragma unroll
      for (int j = 0; j < 8; ++j) ov[j] = (short)f2b(vv[i * 8 + j] * sc);
      *(bf16x8*)&o[i * 8] = ov;
    }
  }
  { // V half -> LDS transposed
    const float* p = kvpre + rowoff + 128 + lg * 32;
    float ss = 0.f;
#pragma unroll
    for (int i = 0; i < 8; ++i) {
      float4 a = *(const float4*)&p[i * 4];
      vv[i * 4 + 0] = a.x; vv[i * 4 + 1] = a.y; vv[i * 4 + 2] = a.z; vv[i * 4 + 3] = a.w;
      ss += a.x * a.x + a.y * a.y + a.z * a.z + a.w * a.w;
    }
    ss += __shfl_xor(ss, 1); ss += __shfl_xor(ss, 2);
    const float sc = rsqrtf(ss + 1e-12f);
#pragma unroll
    for (int i = 0; i < 32; ++i) vtT[lg * 32 + i][lm] = f2b(vv[i] * sc);
  }
  __syncthreads();
  const int d = t >> 1, half = t & 1;
  u16* o = Vt + ((size_t)(b * NH_ + h) * D_ + d) * M_ + mt * 64 + half * 32;
#pragma unroll
  for (int i = 0; i < 4; ++i) {
    bf16x8 ov = *(const bf16x8*)&vtT[d][half * 32 + i * 8];
    *(bf16x8*)&o[i * 8] = ov;
  }
}

// -------------------------------------------------------------- attention
// Barrier-free 1-wave blocks; K/V direct from global (L2-resident per bh);
// packed-bitmask mask; loads BATCHED before each MFMA cluster (one latency
// exposure per phase instead of 16 serial load->use chains).
__global__ __launch_bounds__(64, 2) void attn_k(const u16* __restrict__ Q, const u16* __restrict__ Kq,
                                                const u16* __restrict__ Vt, const u64* __restrict__ BM,
                                                u16* __restrict__ ctx) {
  __shared__ u16 Pl[32 * 72];
  const int l = threadIdx.x, lr = l & 15, lk = l >> 4;
  const int lin = blockIdx.x;
  const int xcd = lin & 7, idx = lin >> 3;
  const int bh = xcd * 4 + (idx >> 6);
  const int sbase = (idx & 63) * 32;
  const int b = bh >> 4, h = bh & 15;
  const u16* Qb = Q + ((size_t)bh * S_ + sbase) * D_;
  bf16x8 qf[2][4];
#pragma unroll
  for (int sf = 0; sf < 2; ++sf)
#pragma unroll
    for (int kc = 0; kc < 4; ++kc)
      qf[sf][kc] = *(const bf16x8*)&Qb[(sf * 16 + lr) * D_ + kc * 32 + lk * 8];
  f32x4 oacc[2][8] = {};
  float den[2][4] = {};
  const u16* Kb = Kq + (size_t)bh * M_ * D_;
  const u16* Vb = Vt + (size_t)bh * D_ * M_;
  const u64* Mb = BM + ((size_t)b * S_ + sbase) * (M_ / 64);
  const float invn = 0.08838834764831845f;

  for (int m0 = 0; m0 < M_; m0 += 64) {
    // ---- batched K loads
    bf16x8 kf[4][4];
#pragma unroll
    for (int mf = 0; mf < 4; ++mf)
#pragma unroll
      for (int kc = 0; kc < 4; ++kc)
        kf[mf][kc] = *(const bf16x8*)&Kb[(size_t)(m0 + mf * 16 + lr) * D_ + kc * 32 + lk * 8];
    f32x4 sc[2][4] = {};
    __builtin_amdgcn_s_setprio(1);
#pragma unroll
    for (int mf = 0; mf < 4; ++mf)
#pragma unroll
      for (int kc = 0; kc < 4; ++kc)
#pragma unroll
        for (int sf = 0; sf < 2; ++sf)
          sc[sf][mf] = __builtin_amdgcn_mfma_f32_16x16x32_bf16(qf[sf][kc], kf[mf][kc], sc[sf][mf], 0, 0, 0);
    __builtin_amdgcn_s_setprio(0);
    // ---- mask + exp + P write
    const int mw = m0 >> 6;
#pragma unroll
    for (int sf = 0; sf < 2; ++sf)
#pragma unroll
      for (int j2 = 0; j2 < 4; ++j2) {
        const int rloc = sf * 16 + lk * 4 + j2;
        const u64 wbits = Mb[(size_t)rloc * (M_ / 64) + mw];
#pragma unroll
        for (int mf = 0; mf < 4; ++mf) {
          float p = __expf(sc[sf][mf][j2] * invn);
          p = ((wbits >> (mf * 16 + lr)) & 1ull) ? p : 0.0f;
          den[sf][j2] += p;
          Pl[rloc * 72 + mf * 16 + lr] = f2b(p);
        }
      }
    // ---- batched V loads (overlap with exp finishing)
    bf16x8 vf[8][2];
#pragma unroll
    for (int nf = 0; nf < 8; ++nf)
#pragma unroll
      for (int kc2 = 0; kc2 < 2; ++kc2)
        vf[nf][kc2] = *(const bf16x8*)&Vb[(size_t)(nf * 16 + lr) * M_ + m0 + (kc2 * 4 + lk) * 8];
    asm volatile("s_waitcnt lgkmcnt(0)" ::: "memory");
    __builtin_amdgcn_sched_barrier(0);
    bf16x8 pa[2][2];
#pragma unroll
    for (int sf = 0; sf < 2; ++sf)
#pragma unroll
      for (int kc2 = 0; kc2 < 2; ++kc2)
        pa[sf][kc2] = *(const bf16x8*)&Pl[(sf * 16 + lr) * 72 + kc2 * 32 + lk * 8];
    __builtin_amdgcn_s_setprio(1);
#pragma unroll
    for (int kc2 = 0; kc2 < 2; ++kc2)
#pragma unroll
      for (int nf = 0; nf < 8; ++nf)
#pragma unroll
        for (int sf = 0; sf < 2; ++sf)
          oacc[sf][nf] = __builtin_amdgcn_mfma_f32_16x16x32_bf16(pa[sf][kc2], vf[nf][kc2], oacc[sf][nf], 0, 0, 0);
    __builtin_amdgcn_s_setprio(0);
  }
#pragma unroll
  for (int sf = 0; sf < 2; ++sf)
#pragma unroll
    for (int j2 = 0; j2 < 4; ++j2) {
      float d = den[sf][j2];
      d += __shfl_xor(d, 1); d += __shfl_xor(d, 2); d += __shfl_xor(d, 4); d += __shfl_xor(d, 8);
      den[sf][j2] = 1.0f / fmaxf(d, 1e-20f);
    }
#pragma unroll
  for (int sf = 0; sf < 2; ++sf)
#pragma unroll
    for (int nf = 0; nf < 8; ++nf)
#pragma unroll
      for (int j2 = 0; j2 < 4; ++j2) {
        int s = sbase + sf * 16 + lk * 4 + j2;
        int dd = nf * 16 + lr;
        ctx[((size_t)s * B_ + b) * H_ + h * D_ + dd] = f2b(oacc[sf][nf][j2] * den[sf][j2]);
      }
}

// ------------------------------------------------------------------- host
extern "C" void kernel_launch(void* const* d_in, const int* in_sizes, int n_in,
                              void* d_out, int out_size, void* d_ws, size_t ws_size,
                              hipStream_t stream) {
  (void)in_sizes; (void)n_in; (void)out_size; (void)ws_size;
  char* ws = (char*)d_ws;
  u16* WT     = (u16*)(ws + 0);            // 33.55 MB  transposed bf16 weights (reused)
  void* MID   = (void*)(ws + 33554432);    // 67.11 MB  mlp mid bf16 / q_pre f32 / kv_pre f32
  float* XF   = (float*)(ws + 100663296);  // 33.55 MB  running x (f32)
  u16* HB     = (u16*)(ws + 134217728);    // 16.78 MB  LN outputs bf16
  u16* MEMB   = (u16*)(ws + 150994944);    // 16.78 MB  mem bf16, later ctx bf16
  u16* QB     = (u16*)(ws + 167772160);    // Q [B][NH][S][D]
  u16* KB     = (u16*)(ws + 184549376);    // K [B][NH][M][D]
  u16* VTB    = (u16*)(ws + 201326592);    // V^T [B][NH][D][M]
  u64* BMB    = (u64*)(ws + 218103808);    // packed mask bitmask
  float* SM   = (float*)(ws + 234881024);
  int* FLAGS  = (int*)(ws + 235044864);

  float* Bias1  = SM + 0;
  float* Bias1o = SM + 8192;
  float* BiasQ  = SM + 10240;
  float* BiasKV = SM + 12288;
  float* BiasD  = SM + 16384;
  float* Bias2  = SM + 18432;
  float* Bias2o = SM + 26624;
  float* G1v = SM + 28672; float* B1v = SM + 30720;
  float* G2v = SM + 32768; float* B2v = SM + 34816;
  float* G3v = SM + 36864; float* B3v = SM + 38912;

  detect_kinds<<<1, 64, 0, stream>>>((const u32*)d_in[0], (const u32*)d_in[2], FLAGS);

  cvt_f32<<<32, 256, 0, stream>>>(d_in[10], FLAGS, Bias1, 8192);
  cvt_f32<<<8, 256, 0, stream>>>(d_in[12], FLAGS, Bias1o, 2048);
  cvt_f32<<<8, 256, 0, stream>>>(d_in[14], FLAGS, BiasQ, 2048);
  cvt_f32<<<16, 256, 0, stream>>>(d_in[16], FLAGS, BiasKV, 4096);
  cvt_f32<<<8, 256, 0, stream>>>(d_in[18], FLAGS, BiasD, 2048);
  cvt_f32<<<32, 256, 0, stream>>>(d_in[20], FLAGS, Bias2, 8192);
  cvt_f32<<<8, 256, 0, stream>>>(d_in[22], FLAGS, Bias2o, 2048);
  cvt_f32<<<8, 256, 0, stream>>>(d_in[3], FLAGS, G1v, 2048);
  cvt_f32<<<8, 256, 0, stream>>>(d_in[4], FLAGS, B1v, 2048);
  cvt_f32<<<8, 256, 0, stream>>>(d_in[5], FLAGS, G2v, 2048);
  cvt_f32<<<8, 256, 0, stream>>>(d_in[6], FLAGS, B2v, 2048);
  cvt_f32<<<8, 256, 0, stream>>>(d_in[7], FLAGS, G3v, 2048);
  cvt_f32<<<8, 256, 0, stream>>>(d_in[8], FLAGS, B3v, 2048);

  mask_bits<<<(B_ * S_ * M_) / 256, 256, 0, stream>>>(d_in[2], FLAGS, BMB);
  cast_in_bf16<<<(MB_ * H_ / 8) / 256, 256, 0, stream>>>(d_in[1], FLAGS, MEMB, MB_ * H_ / 8);

  dim3 blk(256);
  dim3 blk5(512);
  // ---- mlp1: x = mlp(ln1(x))  (no residual)
  layernorm_k<1><<<SB_, blk, 0, stream>>>(d_in[0], FLAGS, G1v, B1v, HB);
  transpose_cast<<<dim3(FF_ / 64, H_ / 64), blk, 0, stream>>>(d_in[9], FLAGS, WT, H_, FF_);
  gemm8p<256, 1, 0, 0, 1, 0><<<dim3(FF_ / 256, SB_ / 256), blk5, 0, stream>>>(HB, WT, Bias1, nullptr, nullptr, (u16*)MID, FLAGS, SB_, FF_, H_);
  transpose_cast<<<dim3(H_ / 64, FF_ / 64), blk, 0, stream>>>(d_in[11], FLAGS, WT, FF_, H_);
  gemm8p<128, 0, 0, 1, 0, 0><<<dim3(H_ / 128, SB_ / 256), blk5, 0, stream>>>((u16*)MID, WT, Bias1o, nullptr, XF, nullptr, FLAGS, SB_, H_, FF_);

  // ---- memory attention
  layernorm_k<0><<<SB_, blk, 0, stream>>>(XF, FLAGS, G2v, B2v, HB);
  transpose_cast<<<dim3(H_ / 64, H_ / 64), blk, 0, stream>>>(d_in[13], FLAGS, WT, H_, H_);
  gemm8p<128, 0, 0, 1, 0, 0><<<dim3(H_ / 128, SB_ / 256), blk5, 0, stream>>>(HB, WT, BiasQ, nullptr, MID, nullptr, FLAGS, SB_, H_, H_);
  l2_q<<<(SB_ * NH_) / 64, blk, 0, stream>>>((const float*)MID, QB);
  transpose_cast<<<dim3(2 * H_ / 64, H_ / 64), blk, 0, stream>>>(d_in[15], FLAGS, WT, H_, 2 * H_);
  gemm8p<256, 0, 0, 1, 0, 0><<<dim3(2 * H_ / 256, MB_ / 256), blk5, 0, stream>>>(MEMB, WT, BiasKV, nullptr, MID, nullptr, FLAGS, MB_, 2 * H_, H_);
  l2_kv<<<B_ * NH_ * (M_ / 64), blk, 0, stream>>>((const float*)MID, KB, VTB);
  attn_k<<<2048, 64, 0, stream>>>(QB, KB, VTB, BMB, MEMB);
  transpose_cast<<<dim3(H_ / 64, H_ / 64), blk, 0, stream>>>(d_in[17], FLAGS, WT, H_, H_);
  gemm8p<128, 0, 1, 1, 0, 0><<<dim3(H_ / 128, SB_ / 256), blk5, 0, stream>>>(MEMB, WT, BiasD, XF, XF, nullptr, FLAGS, SB_, H_, H_);

  // ---- mlp2 with residual
  layernorm_k<0><<<SB_, blk, 0, stream>>>(XF, FLAGS, G3v, B3v, HB);
  transpose_cast<<<dim3(FF_ / 64, H_ / 64), blk, 0, stream>>>(d_in[19], FLAGS, WT, H_, FF_);
  gemm8p<256, 1, 0, 0, 1, 0><<<dim3(FF_ / 256, SB_ / 256), blk5, 0, stream>>>(HB, WT, Bias2, nullptr, nullptr, (u16*)MID, FLAGS, SB_, FF_, H_);
  transpose_cast<<<dim3(H_ / 64, FF_ / 64), blk, 0, stream>>>(d_in[21], FLAGS, WT, FF_, H_);
  gemm8p<128, 0, 1, 1, 0, 1><<<dim3(H_ / 128, SB_ / 256), blk5, 0, stream>>>((u16*)MID, WT, Bias2o, XF, d_out, nullptr, FLAGS, SB_, H_, FF_);
}

// Round 8
// 1266.994 us; speedup vs baseline: 1.1522x; 1.1158x over previous
//
#include <hip/hip_runtime.h>
#include <stdint.h>
#include <stddef.h>

typedef __attribute__((ext_vector_type(8))) short bf16x8;
typedef __attribute__((ext_vector_type(4))) float f32x4;
typedef unsigned short u16;
typedef unsigned int u32;
typedef unsigned long long u64;

static constexpr int S_ = 2048, B_ = 2, H_ = 2048, NH_ = 16, D_ = 128, M_ = 2048, FF_ = 8192;
static constexpr int SB_ = S_ * B_;
static constexpr int MB_ = M_ * B_;

__device__ __forceinline__ float b2f(u16 b) {
  union { u32 u; float f; } v; v.u = ((u32)b) << 16; return v.f;
}
__device__ __forceinline__ u16 f2b(float f) {
  union { float f; u32 u; } v; v.f = f;
  u32 u = v.u;
  return (u16)((u + 0x7FFFu + ((u >> 16) & 1u)) >> 16);
}
__device__ __forceinline__ float geluf(float x) {
  float x3 = x * x * x;
  return 0.5f * x * (1.0f + tanhf(0.7978845608028654f * (x + 0.044715f * x3)));
}

#define LDSP(p) (reinterpret_cast<__attribute__((address_space(3))) uint32_t*>(reinterpret_cast<uintptr_t>(p)))
#define GLBP(p) (reinterpret_cast<const __attribute__((address_space(1))) uint32_t*>(reinterpret_cast<uintptr_t>(p)))

// ---------------------------------------------------------------- detectors
__global__ void detect_kinds(const u32* __restrict__ x0, const u32* __restrict__ mask, int* __restrict__ flags) {
  if (threadIdx.x == 0 && blockIdx.x == 0) {
    int cnt = 0;
    for (int i = 0; i < 256; ++i) {
      u32 e = (x0[i] >> 7) & 0xFFu;
      if (e >= 118u && e <= 130u) ++cnt;
    }
    flags[0] = (cnt >= 128) ? 0 : 1;
    int all01 = 1, allf = 1, allb = 1;
    for (int i = 0; i < 256; ++i) {
      u32 v = mask[i];
      if (v > 1u) all01 = 0;
      if (v != 0u && v != 0x3F800000u) allf = 0;
      u32 lo = v & 0xFFFFu, hi = v >> 16;
      if ((lo != 0u && lo != 0x3F80u) || (hi != 0u && hi != 0x3F80u)) allb = 0;
    }
    flags[1] = all01 ? 1 : (allf ? 3 : (allb ? 2 : 0));
  }
}

// mask -> packed bitmask: bit m = 1 iff UNMASKED
__global__ void mask_bits(const void* __restrict__ mraw, const int* __restrict__ flags, u64* __restrict__ bm) {
  int i = blockIdx.x * 256 + threadIdx.x;
  int kind = flags[1];
  int masked;
  if (kind == 1)      masked = ((const int*)mraw)[i] != 0;
  else if (kind == 3) masked = ((const float*)mraw)[i] != 0.0f;
  else if (kind == 2) masked = ((const u16*)mraw)[i] != 0;
  else                masked = ((const unsigned char*)mraw)[i] != 0;
  u64 vote = __ballot(masked == 0);
  if ((threadIdx.x & 63) == 0) bm[i >> 6] = vote;
}

__global__ void cvt_f32(const void* __restrict__ src, const int* __restrict__ flags, float* __restrict__ dst, int n) {
  int i = blockIdx.x * 256 + threadIdx.x;
  if (i < n) dst[i] = flags[0] ? ((const float*)src)[i] : b2f(((const u16*)src)[i]);
}

__global__ void cast_in_bf16(const void* __restrict__ src, const int* __restrict__ flags, u16* __restrict__ dst, int n8) {
  int i = blockIdx.x * 256 + threadIdx.x;
  if (i >= n8) return;
  if (flags[0]) {
    const float4* p = (const float4*)src;
    float4 a = p[i * 2], c = p[i * 2 + 1];
    bf16x8 o;
    o[0] = (short)f2b(a.x); o[1] = (short)f2b(a.y); o[2] = (short)f2b(a.z); o[3] = (short)f2b(a.w);
    o[4] = (short)f2b(c.x); o[5] = (short)f2b(c.y); o[6] = (short)f2b(c.z); o[7] = (short)f2b(c.w);
    *(bf16x8*)&dst[i * 8] = o;
  } else {
    *(bf16x8*)&dst[i * 8] = ((const bf16x8*)src)[i];
  }
}

// ------------------------------------------------------------ transpose+cast
__global__ __launch_bounds__(256) void transpose_cast(const void* __restrict__ in, const int* __restrict__ flags,
                                                      u16* __restrict__ out, int R, int C) {
  __shared__ u16 tile[64][65];
  const int isf = flags[0];
  const int tr = blockIdx.y * 64, tc = blockIdx.x * 64;
  const int tx = threadIdx.x & 63, ty = threadIdx.x >> 6;
  const float* inf = (const float*)in;
  const u16* inb = (const u16*)in;
#pragma unroll
  for (int i = 0; i < 16; ++i) {
    int r = ty * 16 + i;
    size_t idx = (size_t)(tr + r) * C + tc + tx;
    tile[r][tx] = isf ? f2b(inf[idx]) : inb[idx];
  }
  __syncthreads();
#pragma unroll
  for (int i = 0; i < 16; ++i) {
    int c = ty * 16 + i;
    out[(size_t)(tc + c) * R + tr + tx] = tile[tx][c];
  }
}

// ---------------------------------------------------------------- layernorm
template <int EXT>
__global__ __launch_bounds__(256) void layernorm_k(const void* __restrict__ xin, const int* __restrict__ flags,
                                                   const float* __restrict__ g, const float* __restrict__ bta,
                                                   u16* __restrict__ out) {
  const int row = blockIdx.x, t = threadIdx.x;
  float v[8];
  bool bfmode = EXT && (flags[0] == 0);
  if (bfmode) {
    const u16* xr = (const u16*)xin + (size_t)row * H_ + t * 8;
    bf16x8 a = *(const bf16x8*)xr;
#pragma unroll
    for (int j = 0; j < 8; ++j) v[j] = b2f((u16)a[j]);
  } else {
    const float* xr = (const float*)xin + (size_t)row * H_ + t * 8;
    float4 a = *(const float4*)xr, c = *(const float4*)(xr + 4);
    v[0] = a.x; v[1] = a.y; v[2] = a.z; v[3] = a.w;
    v[4] = c.x; v[5] = c.y; v[6] = c.z; v[7] = c.w;
  }
  float s1 = 0.f, s2 = 0.f;
#pragma unroll
  for (int j = 0; j < 8; ++j) { s1 += v[j]; s2 += v[j] * v[j]; }
#pragma unroll
  for (int off = 32; off > 0; off >>= 1) { s1 += __shfl_down(s1, off); s2 += __shfl_down(s2, off); }
  __shared__ float red[8];
  const int w = t >> 6;
  if ((t & 63) == 0) { red[w] = s1; red[4 + w] = s2; }
  __syncthreads();
  s1 = red[0] + red[1] + red[2] + red[3];
  s2 = red[4] + red[5] + red[6] + red[7];
  const float mean = s1 * (1.0f / H_);
  const float rstd = rsqrtf(s2 * (1.0f / H_) - mean * mean + 1e-5f);
  bf16x8 o;
#pragma unroll
  for (int j = 0; j < 8; ++j) {
    float y = (v[j] - mean) * rstd * g[t * 8 + j] + bta[t * 8 + j];
    o[j] = (short)f2b(y);
  }
  *(bf16x8*)(out + (size_t)row * H_ + t * 8) = o;
}

// ------------------------------------------------------------------- GEMM
// 8-phase 256xBN template (T2+T3+T4+T5) — unchanged from round 7.
template <int BN, int GELU, int RES, int WF, int WB, int ODYN>
__global__ __launch_bounds__(512, 2) void gemm8p(const u16* __restrict__ A, const u16* __restrict__ Bt,
                                                 const float* __restrict__ bias, const float* __restrict__ res,
                                                 void* __restrict__ outF, u16* __restrict__ outB,
                                                 const int* __restrict__ flags, int Mr, int N, int K) {
  constexpr int NBF = (BN == 256) ? 2 : 1;
  __shared__ u16 lds[65536];
  const int t = threadIdx.x;
  const int w = t >> 6, l = t & 63, lr = l & 15, lk = l >> 4;
  const int wr = w >> 2, wc = w & 3;
  const int gx = gridDim.x, gy = gridDim.y;
  const int orig = blockIdx.y * gx + blockIdx.x;
  const int nwg = gx * gy, per = nwg >> 3;
  int tm, tn;
  {
    const int xcd = orig & 7, p = orig >> 3;
    const int ncx = gx >> 3 ? gx >> 3 : 1;
    if ((gx & 7) == 0 && (per & 7) == 0) {
      const int cy = per >> 3;
      const int ccol = xcd % ncx, crow = xcd / ncx;
      const int px = p & 7, py = p >> 3;
      tn = (ccol * 8 + px) * BN;
      tm = (crow * cy + py) * 256;
    } else {
      tn = (orig % gx) * BN;
      tm = (orig / gx) * 256;
    }
  }
  const int r0 = t >> 3;
  const int cl = (t & 7) ^ (r0 & 7);
  const u32 abase = (u32)(tm + r0) * (u32)K + (u32)cl * 8;
  const u32 bbase = (u32)(tn + r0) * (u32)K + (u32)cl * 8;
  const int wdst = w * 512;
  const int cso0 = ((0 + lk) ^ (lr & 7)) * 8;
  const int cso1 = ((4 + lk) ^ (lr & 7)) * 8;
  const int brow0 = (BN == 256) ? ((wc & 1) * 64) : (wc * 32);

  const int NT = K >> 6, NI = NT >> 1;
  f32x4 acc[8][2 * NBF] = {};

#define STGA_(h) do { if ((h) < 2 * NT) {                                                              \
    const int sl_ = ((h) & 3) * 8192;                                                                  \
    const u32 so_ = abase + ((u32)((h) & 1) * 128u) * (u32)K + ((u32)((h) >> 1)) * 64u;                \
    __builtin_amdgcn_global_load_lds(GLBP(A + so_), LDSP(lds + sl_ + wdst), 16, 0, 0);                 \
    __builtin_amdgcn_global_load_lds(GLBP(A + so_ + (u32)64 * (u32)K), LDSP(lds + sl_ + 4096 + wdst), 16, 0, 0); \
  } } while (0)
#define STGB_(h) do {                                                                                  \
    if constexpr (BN == 256) { if ((h) < 2 * NT) {                                                     \
      const int sl_ = 32768 + ((h) & 3) * 8192;                                                        \
      const u32 so_ = bbase + ((u32)((h) & 1) * 128u) * (u32)K + ((u32)((h) >> 1)) * 64u;              \
      __builtin_amdgcn_global_load_lds(GLBP(Bt + so_), LDSP(lds + sl_ + wdst), 16, 0, 0);              \
      __builtin_amdgcn_global_load_lds(GLBP(Bt + so_ + (u32)64 * (u32)K), LDSP(lds + sl_ + 4096 + wdst), 16, 0, 0); \
    } } else { if ((h) < NT) {                                                                         \
      const int sl_ = 32768 + ((h) & 3) * 8192;                                                        \
      const u32 so_ = bbase + ((u32)(h)) * 64u;                                                        \
      __builtin_amdgcn_global_load_lds(GLBP(Bt + so_), LDSP(lds + sl_ + wdst), 16, 0, 0);              \
      __builtin_amdgcn_global_load_lds(GLBP(Bt + so_ + (u32)64 * (u32)K), LDSP(lds + sl_ + 4096 + wdst), 16, 0, 0); \
    } }                                                                                                \
  } while (0)
#define RDA_(dst, mh, sa)                                                                              \
  _Pragma("unroll") for (int mf2 = 0; mf2 < 4; ++mf2) {                                                \
    const u16* p_ = lds + (sa) * 8192 + ((mh) * 64 + mf2 * 16 + lr) * 64;                              \
    dst[mf2][0] = *(const bf16x8*)(p_ + cso0);                                                         \
    dst[mf2][1] = *(const bf16x8*)(p_ + cso1); }
#define RDB_(dst, nh, sb)                                                                              \
  _Pragma("unroll") for (int nf2 = 0; nf2 < NBF; ++nf2) {                                              \
    const u16* p_ = lds + 32768 + (sb) * 8192 + (brow0 + ((nh) * NBF + nf2) * 16 + lr) * 64;           \
    dst[nf2][0] = *(const bf16x8*)(p_ + cso0);                                                         \
    dst[nf2][1] = *(const bf16x8*)(p_ + cso1); }
#define MM_(afX, bqX, mh, nh)                                                                          \
  _Pragma("unroll") for (int kk = 0; kk < 2; ++kk)                                                     \
  _Pragma("unroll") for (int mf2 = 0; mf2 < 4; ++mf2)                                                  \
  _Pragma("unroll") for (int nf2 = 0; nf2 < NBF; ++nf2)                                                \
    acc[(mh) * 4 + mf2][(nh) * NBF + nf2] = __builtin_amdgcn_mfma_f32_16x16x32_bf16(                   \
        afX[mf2][kk], bqX[nf2][kk], acc[(mh) * 4 + mf2][(nh) * NBF + nf2], 0, 0, 0);
#define PHASE_MID()                                                                                    \
  __builtin_amdgcn_s_barrier();                                                                        \
  asm volatile("s_waitcnt lgkmcnt(0)" ::: "memory");                                                   \
  __builtin_amdgcn_sched_barrier(0);                                                                   \
  __builtin_amdgcn_s_setprio(1);
#define PHASE_END()                                                                                    \
  __builtin_amdgcn_s_setprio(0);                                                                       \
  __builtin_amdgcn_sched_barrier(0);                                                                   \
  __builtin_amdgcn_s_barrier();

  if constexpr (BN == 256) {
    STGB_(0); STGA_(0); STGB_(1); STGA_(1); STGB_(2); STGA_(2);
  } else {
    STGB_(0); STGA_(0); STGA_(1); STGB_(1); STGA_(2);
  }
  asm volatile("s_waitcnt vmcnt(4)" ::: "memory");
  __builtin_amdgcn_s_barrier();

  for (int it = 0; it < NI; ++it) {
    const int T0 = it * 2;
    const int saA0 = (2 * T0 + wr) & 3;
    const int saA1 = (2 * T0 + 2 + wr) & 3;
    const int sbB0 = (BN == 256) ? ((2 * T0 + (wc >> 1)) & 3) : (T0 & 3);
    const int sbB1 = (BN == 256) ? ((2 * T0 + 2 + (wc >> 1)) & 3) : ((T0 + 1) & 3);
    const bool last = (it + 1 == NI);
    bf16x8 af[4][2], bq0[NBF][2], bq1[NBF][2];

    RDA_(af, 0, saA0); RDB_(bq0, 0, sbB0);
    if constexpr (BN == 256) STGB_(4 * it + 3); else STGA_(4 * it + 3);
    PHASE_MID(); MM_(af, bq0, 0, 0); PHASE_END();
    RDB_(bq1, 1, sbB0);
    if constexpr (BN == 256) STGA_(4 * it + 3);
    PHASE_MID(); MM_(af, bq1, 0, 1); PHASE_END();
    RDA_(af, 1, saA0);
    if constexpr (BN == 256) STGB_(4 * it + 4); else STGB_(2 * it + 2);
    PHASE_MID(); MM_(af, bq0, 1, 0); PHASE_END();
    STGA_(4 * it + 4);
    __builtin_amdgcn_s_barrier();
    __builtin_amdgcn_s_setprio(1);
    MM_(af, bq1, 1, 1);
    __builtin_amdgcn_s_setprio(0);
    __builtin_amdgcn_sched_barrier(0);
    if (!last) { asm volatile("s_waitcnt vmcnt(4)" ::: "memory"); }
    else       { asm volatile("s_waitcnt vmcnt(0)" ::: "memory"); }
    __builtin_amdgcn_s_barrier();

    RDA_(af, 0, saA1); RDB_(bq0, 0, sbB1);
    if constexpr (BN == 256) STGB_(4 * it + 5); else STGA_(4 * it + 5);
    PHASE_MID(); MM_(af, bq0, 0, 0); PHASE_END();
    RDB_(bq1, 1, sbB1);
    if constexpr (BN == 256) STGA_(4 * it + 5); else STGB_(2 * it + 3);
    PHASE_MID(); MM_(af, bq1, 0, 1); PHASE_END();
    RDA_(af, 1, saA1);
    if constexpr (BN == 256) STGB_(4 * it + 6);
    PHASE_MID(); MM_(af, bq0, 1, 0); PHASE_END();
    STGA_(4 * it + 6);
    __builtin_amdgcn_s_barrier();
    __builtin_amdgcn_s_setprio(1);
    MM_(af, bq1, 1, 1);
    __builtin_amdgcn_s_setprio(0);
    __builtin_amdgcn_sched_barrier(0);
    if (!last) { asm volatile("s_waitcnt vmcnt(4)" ::: "memory"); }
    __builtin_amdgcn_s_barrier();
  }
#undef STGA_
#undef STGB_
#undef RDA_
#undef RDB_
#undef MM_
#undef PHASE_MID
#undef PHASE_END

  const int obf = ODYN ? (flags[0] ? 0 : 1) : 0;
  (void)Mr;
#pragma unroll
  for (int mf = 0; mf < 8; ++mf) {
#pragma unroll
    for (int nf = 0; nf < 2 * NBF; ++nf) {
      const int col = tn + wc * (BN == 256 ? 64 : 32) + nf * 16 + lr;
      const float bv = bias[col];
#pragma unroll
      for (int j = 0; j < 4; ++j) {
        const int rw = tm + wr * 128 + mf * 16 + lk * 4 + j;
        float vv = acc[mf][nf][j] + bv;
        if (RES) vv += res[(size_t)rw * N + col];
        if (GELU) vv = geluf(vv);
        if (WF) {
          if (ODYN && obf) ((u16*)outF)[(size_t)rw * N + col] = f2b(vv);
          else ((float*)outF)[(size_t)rw * N + col] = vv;
        }
        if (WB) outB[(size_t)rw * N + col] = f2b(vv);
      }
    }
  }
}

// --------------------------------------------------------------- l2 norms
__global__ __launch_bounds__(256) void l2_q(const float* __restrict__ qpre, u16* __restrict__ Q) {
  const int t = threadIdx.x;
  const int g = blockIdx.x * 64 + (t >> 2);
  const int lg = t & 3;
  const int h = g & (NH_ - 1), sb = g >> 4;
  const float* p = qpre + (size_t)sb * H_ + h * D_ + lg * 32;
  float vv[32];
  float ss = 0.f;
#pragma unroll
  for (int i = 0; i < 8; ++i) {
    float4 a = *(const float4*)&p[i * 4];
    vv[i * 4 + 0] = a.x; vv[i * 4 + 1] = a.y; vv[i * 4 + 2] = a.z; vv[i * 4 + 3] = a.w;
    ss += a.x * a.x + a.y * a.y + a.z * a.z + a.w * a.w;
  }
  ss += __shfl_xor(ss, 1); ss += __shfl_xor(ss, 2);
  const float sc = rsqrtf(ss + 1e-12f);
  const int s = sb >> 1, b = sb & 1;
  u16* o = Q + ((size_t)(b * NH_ + h) * S_ + s) * D_ + lg * 32;
#pragma unroll
  for (int i = 0; i < 4; ++i) {
    bf16x8 ov;
#pragma unroll
    for (int j = 0; j < 8; ++j) ov[j] = (short)f2b(vv[i * 8 + j] * sc);
    *(bf16x8*)&o[i * 8] = ov;
  }
}

__global__ __launch_bounds__(256) void l2_kv(const float* __restrict__ kvpre, u16* __restrict__ Kq, u16* __restrict__ Vt) {
  __shared__ u16 vtT[128][72];
  const int t = threadIdx.x;
  const int bid = blockIdx.x;
  const int mt = bid & 31, h = (bid >> 5) & 15, b = bid >> 9;
  const int lm = t >> 2, lg = t & 3;
  const int m = mt * 64 + lm;
  const size_t rowoff = (size_t)(m * B_ + b) * (2 * H_) + h * 256;
  float vv[32];
  { // K half
    const float* p = kvpre + rowoff + lg * 32;
    float ss = 0.f;
#pragma unroll
    for (int i = 0; i < 8; ++i) {
      float4 a = *(const float4*)&p[i * 4];
      vv[i * 4 + 0] = a.x; vv[i * 4 + 1] = a.y; vv[i * 4 + 2] = a.z; vv[i * 4 + 3] = a.w;
      ss += a.x * a.x + a.y * a.y + a.z * a.z + a.w * a.w;
    }
    ss += __shfl_xor(ss, 1); ss += __shfl_xor(ss, 2);
    const float sc = rsqrtf(ss + 1e-12f);
    u16* o = Kq + ((size_t)(b * NH_ + h) * M_ + m) * D_ + lg * 32;
#pragma unroll
    for (int i = 0; i < 4; ++i) {
      bf16x8 ov;
#pragma unroll
      for (int j = 0; j < 8; ++j) ov[j] = (short)f2b(vv[i * 8 + j] * sc);
      *(bf16x8*)&o[i * 8] = ov;
    }
  }
  { // V half -> LDS transposed
    const float* p = kvpre + rowoff + 128 + lg * 32;
    float ss = 0.f;
#pragma unroll
    for (int i = 0; i < 8; ++i) {
      float4 a = *(const float4*)&p[i * 4];
      vv[i * 4 + 0] = a.x; vv[i * 4 + 1] = a.y; vv[i * 4 + 2] = a.z; vv[i * 4 + 3] = a.w;
      ss += a.x * a.x + a.y * a.y + a.z * a.z + a.w * a.w;
    }
    ss += __shfl_xor(ss, 1); ss += __shfl_xor(ss, 2);
    const float sc = rsqrtf(ss + 1e-12f);
#pragma unroll
    for (int i = 0; i < 32; ++i) vtT[lg * 32 + i][lm] = f2b(vv[i] * sc);
  }
  __syncthreads();
  const int d = t >> 1, half = t & 1;
  u16* o = Vt + ((size_t)(b * NH_ + h) * D_ + d) * M_ + mt * 64 + half * 32;
#pragma unroll
  for (int i = 0; i < 4; ++i) {
    bf16x8 ov = *(const bf16x8*)&vtT[d][half * 32 + i * 8];
    *(bf16x8*)&o[i * 8] = ov;
  }
}

// -------------------------------------------------------------- attention
// 4 waves x 16 q-rows = 64 rows/block; grid 1024 -> 4 blocks/CU (16 waves/CU).
// K/V staged via coalesced global_load_lds (4 waves amortize L2 line-requests
// 4x vs direct fragment loads), m-tile 32, double-buffered (32KB), ONE
// vmcnt(0)+barrier per tile at end of a long compute phase.  Swizzled K/V
// LDS (conflict-free per quarter-wave); bitmask mask (u32 view); per-wave P
// in LDS padded to 40 u16.
__global__ __launch_bounds__(256, 3) void attn_k(const u16* __restrict__ Q, const u16* __restrict__ Kq,
                                                 const u16* __restrict__ Vt, const u32* __restrict__ BM32,
                                                 u16* __restrict__ ctx) {
  __shared__ u16 Kl[2][4096];   // [32 m][128 d], chunk16B swz c^=(r&7)
  __shared__ u16 Vl[2][4096];   // [128 d][32 m], chunk16B swz c^=((d>>1)&3)
  __shared__ u16 Pl[4][16 * 40];
  const int t = threadIdx.x, w = t >> 6, l = t & 63, lr = l & 15, lk = l >> 4;
  const int lin = blockIdx.x;
  const int xcd = lin & 7, idx = lin >> 3;          // idx 0..127
  const int bh = xcd * 4 + (idx >> 5);              // 4 bh per XCD
  const int chunk = idx & 31;
  const int b = bh >> 4, h = bh & 15;
  const int srow = chunk * 64 + w * 16;             // wave's first q-row
  // Q fragments (one-time)
  const u16* Qb = Q + ((size_t)bh * S_ + srow) * D_;
  bf16x8 qf[4];
#pragma unroll
  for (int kc = 0; kc < 4; ++kc)
    qf[kc] = *(const bf16x8*)&Qb[lr * D_ + kc * 32 + lk * 8];
  f32x4 oacc[8] = {};
  float den[4] = {};
  const u16* Kb = Kq + (size_t)bh * M_ * D_;
  const u16* Vb = Vt + (size_t)bh * D_ * M_;
  const float invn = 0.08838834764831845f;  // 1/sqrt(128)
  // staging source offsets (inverse-swizzled), 2 chunks per thread per operand
  u32 ksrc[2], vsrc[2];
#pragma unroll
  for (int i = 0; i < 2; ++i) {
    const int kidx = i * 256 + t;
    const int kr = kidx >> 4, kc_ = (kidx & 15) ^ (kr & 7);
    ksrc[i] = (u32)kr * D_ + (u32)kc_ * 8;
    const int vidx = i * 256 + t;
    const int vd = vidx >> 2, vc = (vidx & 3) ^ ((vd >> 1) & 3);
    vsrc[i] = (u32)vd * M_ + (u32)vc * 8;
  }
  const int wdst = w * 64 * 8;  // wave-uniform LDS base (u16) per 256-chunk round
  // mask row bases (u32 words; M/32 = 64 words per row)
  u32 mrow[4];
#pragma unroll
  for (int j2 = 0; j2 < 4; ++j2)
    mrow[j2] = ((u32)b * S_ + (u32)(srow + lk * 4 + j2)) * 64u;

#define STG(buf, m0) do {                                                                              \
    _Pragma("unroll")                                                                                  \
    for (int i = 0; i < 2; ++i) {                                                                      \
      __builtin_amdgcn_global_load_lds(GLBP(Kb + (size_t)(m0) * D_ + ksrc[i]),                         \
                                       LDSP(&Kl[buf][i * 2048 + wdst]), 16, 0, 0);                     \
      __builtin_amdgcn_global_load_lds(GLBP(Vb + (size_t)(m0) + vsrc[i]),                              \
                                       LDSP(&Vl[buf][i * 2048 + wdst]), 16, 0, 0);                     \
    }                                                                                                  \
  } while (0)

  STG(0, 0);
  asm volatile("s_waitcnt vmcnt(0)" ::: "memory");
  __builtin_amdgcn_s_barrier();
  int cur = 0;

  for (int t64 = 0; t64 < M_ / 32; ++t64) {
    const int m0 = t64 * 32;
    if (t64 + 1 < M_ / 32) STG(cur ^ 1, m0 + 32);
    // mask words (L2-resident; issued early, consumed after QK)
    u32 mw[4];
#pragma unroll
    for (int j2 = 0; j2 < 4; ++j2) mw[j2] = BM32[mrow[j2] + t64];
    // ---- QK^T from swizzled Kl
    f32x4 sc[2] = {};
#pragma unroll
    for (int mf = 0; mf < 2; ++mf) {
      const int r = mf * 16 + lr;
#pragma unroll
      for (int kc = 0; kc < 4; ++kc) {
        const int cc = ((kc * 4 + lk) ^ (r & 7));
        bf16x8 kfv = *(const bf16x8*)&Kl[cur][r * 128 + cc * 8];
        sc[mf] = __builtin_amdgcn_mfma_f32_16x16x32_bf16(qf[kc], kfv, sc[mf], 0, 0, 0);
      }
    }
    // ---- mask + exp + P write (wave-local)
#pragma unroll
    for (int j2 = 0; j2 < 4; ++j2) {
      const int rloc = lk * 4 + j2;
#pragma unroll
      for (int mf = 0; mf < 2; ++mf) {
        float p = __expf(sc[mf][j2] * invn);
        p = ((mw[j2] >> (mf * 16 + lr)) & 1u) ? p : 0.0f;
        den[j2] += p;
        Pl[w][rloc * 40 + mf * 16 + lr] = f2b(p);
      }
    }
    asm volatile("s_waitcnt lgkmcnt(0)" ::: "memory");
    __builtin_amdgcn_sched_barrier(0);
    // ---- PV from swizzled Vl
    bf16x8 pa = *(const bf16x8*)&Pl[w][lr * 40 + lk * 8];
#pragma unroll
    for (int nf = 0; nf < 8; ++nf) {
      const int d = nf * 16 + lr;
      const int cc = lk ^ ((d >> 1) & 3);
      bf16x8 vfv = *(const bf16x8*)&Vl[cur][d * 32 + cc * 8];
      oacc[nf] = __builtin_amdgcn_mfma_f32_16x16x32_bf16(pa, vfv, oacc[nf], 0, 0, 0);
    }
    asm volatile("s_waitcnt vmcnt(0)" ::: "memory");
    __builtin_amdgcn_s_barrier();
    cur ^= 1;
  }
#undef STG
  // denominator reduce across lr-lanes (rows are per (lk,j2))
#pragma unroll
  for (int j2 = 0; j2 < 4; ++j2) {
    float d = den[j2];
    d += __shfl_xor(d, 1); d += __shfl_xor(d, 2); d += __shfl_xor(d, 4); d += __shfl_xor(d, 8);
    den[j2] = 1.0f / fmaxf(d, 1e-20f);
  }
#pragma unroll
  for (int nf = 0; nf < 8; ++nf)
#pragma unroll
    for (int j2 = 0; j2 < 4; ++j2) {
      const int s = srow + lk * 4 + j2;
      const int dd = nf * 16 + lr;
      ctx[((size_t)s * B_ + b) * H_ + h * D_ + dd] = f2b(oacc[nf][j2] * den[j2]);
    }
}

// ------------------------------------------------------------------- host
extern "C" void kernel_launch(void* const* d_in, const int* in_sizes, int n_in,
                              void* d_out, int out_size, void* d_ws, size_t ws_size,
                              hipStream_t stream) {
  (void)in_sizes; (void)n_in; (void)out_size; (void)ws_size;
  char* ws = (char*)d_ws;
  u16* WT     = (u16*)(ws + 0);
  void* MID   = (void*)(ws + 33554432);
  float* XF   = (float*)(ws + 100663296);
  u16* HB     = (u16*)(ws + 134217728);
  u16* MEMB   = (u16*)(ws + 150994944);
  u16* QB     = (u16*)(ws + 167772160);
  u16* KB     = (u16*)(ws + 184549376);
  u16* VTB    = (u16*)(ws + 201326592);
  u64* BMB    = (u64*)(ws + 218103808);
  float* SM   = (float*)(ws + 234881024);
  int* FLAGS  = (int*)(ws + 235044864);

  float* Bias1  = SM + 0;
  float* Bias1o = SM + 8192;
  float* BiasQ  = SM + 10240;
  float* BiasKV = SM + 12288;
  float* BiasD  = SM + 16384;
  float* Bias2  = SM + 18432;
  float* Bias2o = SM + 26624;
  float* G1v = SM + 28672; float* B1v = SM + 30720;
  float* G2v = SM + 32768; float* B2v = SM + 34816;
  float* G3v = SM + 36864; float* B3v = SM + 38912;

  detect_kinds<<<1, 64, 0, stream>>>((const u32*)d_in[0], (const u32*)d_in[2], FLAGS);

  cvt_f32<<<32, 256, 0, stream>>>(d_in[10], FLAGS, Bias1, 8192);
  cvt_f32<<<8, 256, 0, stream>>>(d_in[12], FLAGS, Bias1o, 2048);
  cvt_f32<<<8, 256, 0, stream>>>(d_in[14], FLAGS, BiasQ, 2048);
  cvt_f32<<<16, 256, 0, stream>>>(d_in[16], FLAGS, BiasKV, 4096);
  cvt_f32<<<8, 256, 0, stream>>>(d_in[18], FLAGS, BiasD, 2048);
  cvt_f32<<<32, 256, 0, stream>>>(d_in[20], FLAGS, Bias2, 8192);
  cvt_f32<<<8, 256, 0, stream>>>(d_in[22], FLAGS, Bias2o, 2048);
  cvt_f32<<<8, 256, 0, stream>>>(d_in[3], FLAGS, G1v, 2048);
  cvt_f32<<<8, 256, 0, stream>>>(d_in[4], FLAGS, B1v, 2048);
  cvt_f32<<<8, 256, 0, stream>>>(d_in[5], FLAGS, G2v, 2048);
  cvt_f32<<<8, 256, 0, stream>>>(d_in[6], FLAGS, B2v, 2048);
  cvt_f32<<<8, 256, 0, stream>>>(d_in[7], FLAGS, G3v, 2048);
  cvt_f32<<<8, 256, 0, stream>>>(d_in[8], FLAGS, B3v, 2048);

  mask_bits<<<(B_ * S_ * M_) / 256, 256, 0, stream>>>(d_in[2], FLAGS, BMB);
  cast_in_bf16<<<(MB_ * H_ / 8) / 256, 256, 0, stream>>>(d_in[1], FLAGS, MEMB, MB_ * H_ / 8);

  dim3 blk(256);
  dim3 blk5(512);
  // ---- mlp1
  layernorm_k<1><<<SB_, blk, 0, stream>>>(d_in[0], FLAGS, G1v, B1v, HB);
  transpose_cast<<<dim3(FF_ / 64, H_ / 64), blk, 0, stream>>>(d_in[9], FLAGS, WT, H_, FF_);
  gemm8p<256, 1, 0, 0, 1, 0><<<dim3(FF_ / 256, SB_ / 256), blk5, 0, stream>>>(HB, WT, Bias1, nullptr, nullptr, (u16*)MID, FLAGS, SB_, FF_, H_);
  transpose_cast<<<dim3(H_ / 64, FF_ / 64), blk, 0, stream>>>(d_in[11], FLAGS, WT, FF_, H_);
  gemm8p<128, 0, 0, 1, 0, 0><<<dim3(H_ / 128, SB_ / 256), blk5, 0, stream>>>((u16*)MID, WT, Bias1o, nullptr, XF, nullptr, FLAGS, SB_, H_, FF_);

  // ---- memory attention
  layernorm_k<0><<<SB_, blk, 0, stream>>>(XF, FLAGS, G2v, B2v, HB);
  transpose_cast<<<dim3(H_ / 64, H_ / 64), blk, 0, stream>>>(d_in[13], FLAGS, WT, H_, H_);
  gemm8p<128, 0, 0, 1, 0, 0><<<dim3(H_ / 128, SB_ / 256), blk5, 0, stream>>>(HB, WT, BiasQ, nullptr, MID, nullptr, FLAGS, SB_, H_, H_);
  l2_q<<<(SB_ * NH_) / 64, blk, 0, stream>>>((const float*)MID, QB);
  transpose_cast<<<dim3(2 * H_ / 64, H_ / 64), blk, 0, stream>>>(d_in[15], FLAGS, WT, H_, 2 * H_);
  gemm8p<256, 0, 0, 1, 0, 0><<<dim3(2 * H_ / 256, MB_ / 256), blk5, 0, stream>>>(MEMB, WT, BiasKV, nullptr, MID, nullptr, FLAGS, MB_, 2 * H_, H_);
  l2_kv<<<B_ * NH_ * (M_ / 64), blk, 0, stream>>>((const float*)MID, KB, VTB);
  attn_k<<<1024, blk, 0, stream>>>(QB, KB, VTB, (const u32*)BMB, MEMB);
  transpose_cast<<<dim3(H_ / 64, H_ / 64), blk, 0, stream>>>(d_in[17], FLAGS, WT, H_, H_);
  gemm8p<128, 0, 1, 1, 0, 0><<<dim3(H_ / 128, SB_ / 256), blk5, 0, stream>>>(MEMB, WT, BiasD, XF, XF, nullptr, FLAGS, SB_, H_, H_);

  // ---- mlp2
  layernorm_k<0><<<SB_, blk, 0, stream>>>(XF, FLAGS, G3v, B3v, HB);
  transpose_cast<<<dim3(FF_ / 64, H_ / 64), blk, 0, stream>>>(d_in[19], FLAGS, WT, H_, FF_);
  gemm8p<256, 1, 0, 0, 1, 0><<<dim3(FF_ / 256, SB_ / 256), blk5, 0, stream>>>(HB, WT, Bias2, nullptr, nullptr, (u16*)MID, FLAGS, SB_, FF_, H_);
  transpose_cast<<<dim3(H_ / 64, FF_ / 64), blk, 0, stream>>>(d_in[21], FLAGS, WT, FF_, H_);
  gemm8p<128, 0, 1, 1, 0, 1><<<dim3(H_ / 128, SB_ / 256), blk5, 0, stream>>>((u16*)MID, WT, Bias2o, XF, d_out, nullptr, FLAGS, SB_, H_, FF_);
}

// Round 9
// 1250.592 us; speedup vs baseline: 1.1673x; 1.0131x over previous
//
#include <hip/hip_runtime.h>
#include <stdint.h>
#include <stddef.h>

typedef __attribute__((ext_vector_type(8))) short bf16x8;
typedef __attribute__((ext_vector_type(4))) float f32x4;
typedef unsigned short u16;
typedef unsigned int u32;
typedef unsigned long long u64;

static constexpr int S_ = 2048, B_ = 2, H_ = 2048, NH_ = 16, D_ = 128, M_ = 2048, FF_ = 8192;
static constexpr int SB_ = S_ * B_;
static constexpr int MB_ = M_ * B_;

__device__ __forceinline__ float b2f(u16 b) {
  union { u32 u; float f; } v; v.u = ((u32)b) << 16; return v.f;
}
__device__ __forceinline__ u16 f2b(float f) {
  union { float f; u32 u; } v; v.f = f;
  u32 u = v.u;
  return (u16)((u + 0x7FFFu + ((u >> 16) & 1u)) >> 16);
}
__device__ __forceinline__ float geluf(float x) {
  float x3 = x * x * x;
  return 0.5f * x * (1.0f + tanhf(0.7978845608028654f * (x + 0.044715f * x3)));
}

#define LDSP(p) (reinterpret_cast<__attribute__((address_space(3))) uint32_t*>(reinterpret_cast<uintptr_t>(p)))
#define GLBP(p) (reinterpret_cast<const __attribute__((address_space(1))) uint32_t*>(reinterpret_cast<uintptr_t>(p)))

// ---------------------------------------------------------------- detectors
__global__ void detect_kinds(const u32* __restrict__ x0, const u32* __restrict__ mask, int* __restrict__ flags) {
  if (threadIdx.x == 0 && blockIdx.x == 0) {
    int cnt = 0;
    for (int i = 0; i < 256; ++i) {
      u32 e = (x0[i] >> 7) & 0xFFu;
      if (e >= 118u && e <= 130u) ++cnt;
    }
    flags[0] = (cnt >= 128) ? 0 : 1;
    int all01 = 1, allf = 1, allb = 1;
    for (int i = 0; i < 256; ++i) {
      u32 v = mask[i];
      if (v > 1u) all01 = 0;
      if (v != 0u && v != 0x3F800000u) allf = 0;
      u32 lo = v & 0xFFFFu, hi = v >> 16;
      if ((lo != 0u && lo != 0x3F80u) || (hi != 0u && hi != 0x3F80u)) allb = 0;
    }
    flags[1] = all01 ? 1 : (allf ? 3 : (allb ? 2 : 0));
  }
}

// mask -> packed bitmask: bit m = 1 iff UNMASKED
__global__ void mask_bits(const void* __restrict__ mraw, const int* __restrict__ flags, u64* __restrict__ bm) {
  int i = blockIdx.x * 256 + threadIdx.x;
  int kind = flags[1];
  int masked;
  if (kind == 1)      masked = ((const int*)mraw)[i] != 0;
  else if (kind == 3) masked = ((const float*)mraw)[i] != 0.0f;
  else if (kind == 2) masked = ((const u16*)mraw)[i] != 0;
  else                masked = ((const unsigned char*)mraw)[i] != 0;
  u64 vote = __ballot(masked == 0);
  if ((threadIdx.x & 63) == 0) bm[i >> 6] = vote;
}

// one launch for all 13 small f32 param conversions
__global__ void cvt_all(const void* s0, const void* s1, const void* s2, const void* s3,
                        const void* s4, const void* s5, const void* s6, const void* s7,
                        const void* s8, const void* s9, const void* s10, const void* s11,
                        const void* s12, const int* __restrict__ flags, float* __restrict__ SM) {
  const int i = blockIdx.x * 256 + threadIdx.x;
  if (i >= 40960) return;
  const void* src; int off;
  if (i < 8192)       { src = s0;  off = 0; }
  else if (i < 10240) { src = s1;  off = 8192; }
  else if (i < 12288) { src = s2;  off = 10240; }
  else if (i < 16384) { src = s3;  off = 12288; }
  else if (i < 18432) { src = s4;  off = 16384; }
  else if (i < 26624) { src = s5;  off = 18432; }
  else if (i < 28672) { src = s6;  off = 26624; }
  else if (i < 30720) { src = s7;  off = 28672; }
  else if (i < 32768) { src = s8;  off = 30720; }
  else if (i < 34816) { src = s9;  off = 32768; }
  else if (i < 36864) { src = s10; off = 34816; }
  else if (i < 38912) { src = s11; off = 36864; }
  else                { src = s12; off = 38912; }
  const int j = i - off;
  SM[i] = flags[0] ? ((const float*)src)[j] : b2f(((const u16*)src)[j]);
}

__global__ void cast_in_bf16(const void* __restrict__ src, const int* __restrict__ flags, u16* __restrict__ dst, int n8) {
  int i = blockIdx.x * 256 + threadIdx.x;
  if (i >= n8) return;
  if (flags[0]) {
    const float4* p = (const float4*)src;
    float4 a = p[i * 2], c = p[i * 2 + 1];
    bf16x8 o;
    o[0] = (short)f2b(a.x); o[1] = (short)f2b(a.y); o[2] = (short)f2b(a.z); o[3] = (short)f2b(a.w);
    o[4] = (short)f2b(c.x); o[5] = (short)f2b(c.y); o[6] = (short)f2b(c.z); o[7] = (short)f2b(c.w);
    *(bf16x8*)&dst[i * 8] = o;
  } else {
    *(bf16x8*)&dst[i * 8] = ((const bf16x8*)src)[i];
  }
}

// ------------------------------------------------------------ transpose+cast
__global__ __launch_bounds__(256) void transpose_cast(const void* __restrict__ in, const int* __restrict__ flags,
                                                      u16* __restrict__ out, int R, int C) {
  __shared__ u16 tile[64][65];
  const int isf = flags[0];
  const int tr = blockIdx.y * 64, tc = blockIdx.x * 64;
  const int tx = threadIdx.x & 63, ty = threadIdx.x >> 6;
  const float* inf = (const float*)in;
  const u16* inb = (const u16*)in;
#pragma unroll
  for (int i = 0; i < 16; ++i) {
    int r = ty * 16 + i;
    size_t idx = (size_t)(tr + r) * C + tc + tx;
    tile[r][tx] = isf ? f2b(inf[idx]) : inb[idx];
  }
  __syncthreads();
#pragma unroll
  for (int i = 0; i < 16; ++i) {
    int c = ty * 16 + i;
    out[(size_t)(tc + c) * R + tr + tx] = tile[tx][c];
  }
}

// ---------------------------------------------------------------- layernorm
template <int EXT>
__global__ __launch_bounds__(256) void layernorm_k(const void* __restrict__ xin, const int* __restrict__ flags,
                                                   const float* __restrict__ g, const float* __restrict__ bta,
                                                   u16* __restrict__ out) {
  const int row = blockIdx.x, t = threadIdx.x;
  float v[8];
  bool bfmode = EXT && (flags[0] == 0);
  if (bfmode) {
    const u16* xr = (const u16*)xin + (size_t)row * H_ + t * 8;
    bf16x8 a = *(const bf16x8*)xr;
#pragma unroll
    for (int j = 0; j < 8; ++j) v[j] = b2f((u16)a[j]);
  } else {
    const float* xr = (const float*)xin + (size_t)row * H_ + t * 8;
    float4 a = *(const float4*)xr, c = *(const float4*)(xr + 4);
    v[0] = a.x; v[1] = a.y; v[2] = a.z; v[3] = a.w;
    v[4] = c.x; v[5] = c.y; v[6] = c.z; v[7] = c.w;
  }
  float s1 = 0.f, s2 = 0.f;
#pragma unroll
  for (int j = 0; j < 8; ++j) { s1 += v[j]; s2 += v[j] * v[j]; }
#pragma unroll
  for (int off = 32; off > 0; off >>= 1) { s1 += __shfl_down(s1, off); s2 += __shfl_down(s2, off); }
  __shared__ float red[8];
  const int w = t >> 6;
  if ((t & 63) == 0) { red[w] = s1; red[4 + w] = s2; }
  __syncthreads();
  s1 = red[0] + red[1] + red[2] + red[3];
  s2 = red[4] + red[5] + red[6] + red[7];
  const float mean = s1 * (1.0f / H_);
  const float rstd = rsqrtf(s2 * (1.0f / H_) - mean * mean + 1e-5f);
  bf16x8 o;
#pragma unroll
  for (int j = 0; j < 8; ++j) {
    float y = (v[j] - mean) * rstd * g[t * 8 + j] + bta[t * 8 + j];
    o[j] = (short)f2b(y);
  }
  *(bf16x8*)(out + (size_t)row * H_ + t * 8) = o;
}

// ------------------------------------------------------------------- GEMM
// 8-phase 256xBN (T2+T3+T4+T5), DEEP staging: tile T stages tile T+2's
// half-tiles (B at P3, A at P4) -> every load has >=4 phases of latency
// cover; vmcnt(8) [BN=256] / vmcnt(6) [BN=128] at P4/P8 keeps exactly the
// just-issued stages in flight and never drains mid-loop; exact vmcnt(0)
// in the tail when stages are guarded off.  Write-after-read safe: a slot's
// last ds_read drains at its phase's lgkmcnt(0), one full barrier before
// the overwriting stage issues.
template <int BN, int GELU, int RES, int WF, int WB, int ODYN>
__global__ __launch_bounds__(512, 2) void gemm8p(const u16* __restrict__ A, const u16* __restrict__ Bt,
                                                 const float* __restrict__ bias, const float* __restrict__ res,
                                                 void* __restrict__ outF, u16* __restrict__ outB,
                                                 const int* __restrict__ flags, int Mr, int N, int K) {
  constexpr int NBF = (BN == 256) ? 2 : 1;
  __shared__ u16 lds[65536];
  const int t = threadIdx.x;
  const int w = t >> 6, l = t & 63, lr = l & 15, lk = l >> 4;
  const int wr = w >> 2, wc = w & 3;
  const int gx = gridDim.x, gy = gridDim.y;
  const int orig = blockIdx.y * gx + blockIdx.x;
  const int nwg = gx * gy, per = nwg >> 3;
  int tm, tn;
  {
    const int xcd = orig & 7, p = orig >> 3;
    const int ncx = gx >> 3 ? gx >> 3 : 1;
    if ((gx & 7) == 0 && (per & 7) == 0) {
      const int cy = per >> 3;
      const int ccol = xcd % ncx, crow = xcd / ncx;
      const int px = p & 7, py = p >> 3;
      tn = (ccol * 8 + px) * BN;
      tm = (crow * cy + py) * 256;
    } else {
      tn = (orig % gx) * BN;
      tm = (orig / gx) * 256;
    }
  }
  const int r0 = t >> 3;
  const int cl = (t & 7) ^ (r0 & 7);
  const u32 abase = (u32)(tm + r0) * (u32)K + (u32)cl * 8;
  const u32 bbase = (u32)(tn + r0) * (u32)K + (u32)cl * 8;
  const int wdst = w * 512;
  const int cso0 = ((0 + lk) ^ (lr & 7)) * 8;
  const int cso1 = ((4 + lk) ^ (lr & 7)) * 8;
  const int brow0 = (BN == 256) ? ((wc & 1) * 64) : (wc * 32);

  const int NT = K >> 6, NI = NT >> 1;
  f32x4 acc[8][2 * NBF] = {};

  // A half-tile h: rows (h&1)*128, K-cols (h>>1)*64; slot h&3 (16KB)
#define STGA_(h) do { if ((h) < 2 * NT) {                                                              \
    const int sl_ = ((h) & 3) * 8192;                                                                  \
    const u32 so_ = abase + ((u32)((h) & 1) * 128u) * (u32)K + ((u32)((h) >> 1)) * 64u;                \
    __builtin_amdgcn_global_load_lds(GLBP(A + so_), LDSP(lds + sl_ + wdst), 16, 0, 0);                 \
    __builtin_amdgcn_global_load_lds(GLBP(A + so_ + (u32)64 * (u32)K), LDSP(lds + sl_ + 4096 + wdst), 16, 0, 0); \
  } } while (0)
  // BN=256: B half-tile h mirrors A.  BN=128: B "half" index = tile index.
#define STGB_(h) do {                                                                                  \
    if constexpr (BN == 256) { if ((h) < 2 * NT) {                                                     \
      const int sl_ = 32768 + ((h) & 3) * 8192;                                                        \
      const u32 so_ = bbase + ((u32)((h) & 1) * 128u) * (u32)K + ((u32)((h) >> 1)) * 64u;              \
      __builtin_amdgcn_global_load_lds(GLBP(Bt + so_), LDSP(lds + sl_ + wdst), 16, 0, 0);              \
      __builtin_amdgcn_global_load_lds(GLBP(Bt + so_ + (u32)64 * (u32)K), LDSP(lds + sl_ + 4096 + wdst), 16, 0, 0); \
    } } else { if ((h) < NT) {                                                                         \
      const int sl_ = 32768 + ((h) & 3) * 8192;                                                        \
      const u32 so_ = bbase + ((u32)(h)) * 64u;                                                        \
      __builtin_amdgcn_global_load_lds(GLBP(Bt + so_), LDSP(lds + sl_ + wdst), 16, 0, 0);              \
      __builtin_amdgcn_global_load_lds(GLBP(Bt + so_ + (u32)64 * (u32)K), LDSP(lds + sl_ + 4096 + wdst), 16, 0, 0); \
    } }                                                                                                \
  } while (0)
#define RDA_(dst, mh, sa)                                                                              \
  _Pragma("unroll") for (int mf2 = 0; mf2 < 4; ++mf2) {                                                \
    const u16* p_ = lds + (sa) * 8192 + ((mh) * 64 + mf2 * 16 + lr) * 64;                              \
    dst[mf2][0] = *(const bf16x8*)(p_ + cso0);                                                         \
    dst[mf2][1] = *(const bf16x8*)(p_ + cso1); }
#define RDB_(dst, nh, sb)                                                                              \
  _Pragma("unroll") for (int nf2 = 0; nf2 < NBF; ++nf2) {                                              \
    const u16* p_ = lds + 32768 + (sb) * 8192 + (brow0 + ((nh) * NBF + nf2) * 16 + lr) * 64;           \
    dst[nf2][0] = *(const bf16x8*)(p_ + cso0);                                                         \
    dst[nf2][1] = *(const bf16x8*)(p_ + cso1); }
#define MM_(afX, bqX, mh, nh)                                                                          \
  _Pragma("unroll") for (int kk = 0; kk < 2; ++kk)                                                     \
  _Pragma("unroll") for (int mf2 = 0; mf2 < 4; ++mf2)                                                  \
  _Pragma("unroll") for (int nf2 = 0; nf2 < NBF; ++nf2)                                                \
    acc[(mh) * 4 + mf2][(nh) * NBF + nf2] = __builtin_amdgcn_mfma_f32_16x16x32_bf16(                   \
        afX[mf2][kk], bqX[nf2][kk], acc[(mh) * 4 + mf2][(nh) * NBF + nf2], 0, 0, 0);
#define PHASE_MID()                                                                                    \
  __builtin_amdgcn_s_barrier();                                                                        \
  asm volatile("s_waitcnt lgkmcnt(0)" ::: "memory");                                                   \
  __builtin_amdgcn_sched_barrier(0);                                                                   \
  __builtin_amdgcn_s_setprio(1);
#define PHASE_END()                                                                                    \
  __builtin_amdgcn_s_setprio(0);                                                                       \
  __builtin_amdgcn_s_barrier();
#define VMW_FULL()                                                                                     \
  if constexpr (BN == 256) { asm volatile("s_waitcnt vmcnt(8)" ::: "memory"); }                        \
  else                     { asm volatile("s_waitcnt vmcnt(6)" ::: "memory"); }

  // ---- prologue: stage tiles 0 and 1 fully; wait for tile 0 only
  if constexpr (BN == 256) {
    STGB_(0); STGB_(1); STGA_(0); STGA_(1);
    STGB_(2); STGB_(3); STGA_(2); STGA_(3);
    asm volatile("s_waitcnt vmcnt(8)" ::: "memory");
  } else {
    STGB_(0); STGA_(0); STGA_(1);
    STGB_(1); STGA_(2); STGA_(3);
    asm volatile("s_waitcnt vmcnt(6)" ::: "memory");
  }
  __builtin_amdgcn_s_barrier();

  for (int it = 0; it < NI; ++it) {
    const int T0 = it * 2;
    bf16x8 af[4][2], bq0[NBF][2], bq1[NBF][2];

    // ================= tile T0 =================
    {
      const int sa = (2 * T0 + wr) & 3;
      const int sb = (BN == 256) ? ((2 * T0 + (wc >> 1)) & 3) : (T0 & 3);
      // P1: A(m0) + B(n0) reads
      RDA_(af, 0, sa); RDB_(bq0, 0, sb);
      PHASE_MID(); MM_(af, bq0, 0, 0); PHASE_END();
      // P2: B(n1) reads
      RDB_(bq1, 1, sb);
      PHASE_MID(); MM_(af, bq1, 0, 1); PHASE_END();
      // P3: A(m1) reads + stage B halves of tile T0+2
      RDA_(af, 1, sa);
      if constexpr (BN == 256) { STGB_(2 * T0 + 4); STGB_(2 * T0 + 5); }
      else                     { STGB_(T0 + 2); }
      PHASE_MID(); MM_(af, bq0, 1, 0); PHASE_END();
      // P4: stage A halves of tile T0+2 + counted vmcnt
      STGA_(2 * T0 + 4); STGA_(2 * T0 + 5);
      __builtin_amdgcn_s_barrier();
      __builtin_amdgcn_s_setprio(1);
      MM_(af, bq1, 1, 1);
      __builtin_amdgcn_s_setprio(0);
      if (T0 + 2 < NT) { VMW_FULL(); }
      else             { asm volatile("s_waitcnt vmcnt(0)" ::: "memory"); }
      __builtin_amdgcn_s_barrier();
    }
    // ================= tile T0+1 =================
    {
      const int T1 = T0 + 1;
      const int sa = (2 * T1 + wr) & 3;
      const int sb = (BN == 256) ? ((2 * T1 + (wc >> 1)) & 3) : (T1 & 3);
      // P5
      RDA_(af, 0, sa); RDB_(bq0, 0, sb);
      PHASE_MID(); MM_(af, bq0, 0, 0); PHASE_END();
      // P6
      RDB_(bq1, 1, sb);
      PHASE_MID(); MM_(af, bq1, 0, 1); PHASE_END();
      // P7: stage B of tile T1+2
      RDA_(af, 1, sa);
      if constexpr (BN == 256) { STGB_(2 * T1 + 4); STGB_(2 * T1 + 5); }
      else                     { STGB_(T1 + 2); }
      PHASE_MID(); MM_(af, bq0, 1, 0); PHASE_END();
      // P8: stage A of tile T1+2 + counted vmcnt
      STGA_(2 * T1 + 4); STGA_(2 * T1 + 5);
      __builtin_amdgcn_s_barrier();
      __builtin_amdgcn_s_setprio(1);
      MM_(af, bq1, 1, 1);
      __builtin_amdgcn_s_setprio(0);
      if (T1 + 2 < NT) { VMW_FULL(); }
      else             { asm volatile("s_waitcnt vmcnt(0)" ::: "memory"); }
      __builtin_amdgcn_s_barrier();
    }
  }
#undef STGA_
#undef STGB_
#undef RDA_
#undef RDB_
#undef MM_
#undef PHASE_MID
#undef PHASE_END
#undef VMW_FULL

  const int obf = ODYN ? (flags[0] ? 0 : 1) : 0;
  (void)Mr;
#pragma unroll
  for (int mf = 0; mf < 8; ++mf) {
#pragma unroll
    for (int nf = 0; nf < 2 * NBF; ++nf) {
      const int col = tn + wc * (BN == 256 ? 64 : 32) + nf * 16 + lr;
      const float bv = bias[col];
#pragma unroll
      for (int j = 0; j < 4; ++j) {
        const int rw = tm + wr * 128 + mf * 16 + lk * 4 + j;
        float vv = acc[mf][nf][j] + bv;
        if (RES) vv += res[(size_t)rw * N + col];
        if (GELU) vv = geluf(vv);
        if (WF) {
          if (ODYN && obf) ((u16*)outF)[(size_t)rw * N + col] = f2b(vv);
          else ((float*)outF)[(size_t)rw * N + col] = vv;
        }
        if (WB) outB[(size_t)rw * N + col] = f2b(vv);
      }
    }
  }
}

// --------------------------------------------------------------- l2 norms
__global__ __launch_bounds__(256) void l2_q(const float* __restrict__ qpre, u16* __restrict__ Q) {
  const int t = threadIdx.x;
  const int g = blockIdx.x * 64 + (t >> 2);
  const int lg = t & 3;
  const int h = g & (NH_ - 1), sb = g >> 4;
  const float* p = qpre + (size_t)sb * H_ + h * D_ + lg * 32;
  float vv[32];
  float ss = 0.f;
#pragma unroll
  for (int i = 0; i < 8; ++i) {
    float4 a = *(const float4*)&p[i * 4];
    vv[i * 4 + 0] = a.x; vv[i * 4 + 1] = a.y; vv[i * 4 + 2] = a.z; vv[i * 4 + 3] = a.w;
    ss += a.x * a.x + a.y * a.y + a.z * a.z + a.w * a.w;
  }
  ss += __shfl_xor(ss, 1); ss += __shfl_xor(ss, 2);
  const float sc = rsqrtf(ss + 1e-12f);
  const int s = sb >> 1, b = sb & 1;
  u16* o = Q + ((size_t)(b * NH_ + h) * S_ + s) * D_ + lg * 32;
#pragma unroll
  for (int i = 0; i < 4; ++i) {
    bf16x8 ov;
#pragma unroll
    for (int j = 0; j < 8; ++j) ov[j] = (short)f2b(vv[i * 8 + j] * sc);
    *(bf16x8*)&o[i * 8] = ov;
  }
}

__global__ __launch_bounds__(256) void l2_kv(const float* __restrict__ kvpre, u16* __restrict__ Kq, u16* __restrict__ Vt) {
  __shared__ u16 vtT[128][72];
  const int t = threadIdx.x;
  const int bid = blockIdx.x;
  const int mt = bid & 31, h = (bid >> 5) & 15, b = bid >> 9;
  const int lm = t >> 2, lg = t & 3;
  const int m = mt * 64 + lm;
  const size_t rowoff = (size_t)(m * B_ + b) * (2 * H_) + h * 256;
  float vv[32];
  { // K half
    const float* p = kvpre + rowoff + lg * 32;
    float ss = 0.f;
#pragma unroll
    for (int i = 0; i < 8; ++i) {
      float4 a = *(const float4*)&p[i * 4];
      vv[i * 4 + 0] = a.x; vv[i * 4 + 1] = a.y; vv[i * 4 + 2] = a.z; vv[i * 4 + 3] = a.w;
      ss += a.x * a.x + a.y * a.y + a.z * a.z + a.w * a.w;
    }
    ss += __shfl_xor(ss, 1); ss += __shfl_xor(ss, 2);
    const float sc = rsqrtf(ss + 1e-12f);
    u16* o = Kq + ((size_t)(b * NH_ + h) * M_ + m) * D_ + lg * 32;
#pragma unroll
    for (int i = 0; i < 4; ++i) {
      bf16x8 ov;
#pragma unroll
      for (int j = 0; j < 8; ++j) ov[j] = (short)f2b(vv[i * 8 + j] * sc);
      *(bf16x8*)&o[i * 8] = ov;
    }
  }
  { // V half -> LDS transposed
    const float* p = kvpre + rowoff + 128 + lg * 32;
    float ss = 0.f;
#pragma unroll
    for (int i = 0; i < 8; ++i) {
      float4 a = *(const float4*)&p[i * 4];
      vv[i * 4 + 0] = a.x; vv[i * 4 + 1] = a.y; vv[i * 4 + 2] = a.z; vv[i * 4 + 3] = a.w;
      ss += a.x * a.x + a.y * a.y + a.z * a.z + a.w * a.w;
    }
    ss += __shfl_xor(ss, 1); ss += __shfl_xor(ss, 2);
    const float sc = rsqrtf(ss + 1e-12f);
#pragma unroll
    for (int i = 0; i < 32; ++i) vtT[lg * 32 + i][lm] = f2b(vv[i] * sc);
  }
  __syncthreads();
  const int d = t >> 1, half = t & 1;
  u16* o = Vt + ((size_t)(b * NH_ + h) * D_ + d) * M_ + mt * 64 + half * 32;
#pragma unroll
  for (int i = 0; i < 4; ++i) {
    bf16x8 ov = *(const bf16x8*)&vtT[d][half * 32 + i * 8];
    *(bf16x8*)&o[i * 8] = ov;
  }
}

// -------------------------------------------------------------- attention
// unchanged from round 8 (verified working)
__global__ __launch_bounds__(256, 3) void attn_k(const u16* __restrict__ Q, const u16* __restrict__ Kq,
                                                 const u16* __restrict__ Vt, const u32* __restrict__ BM32,
                                                 u16* __restrict__ ctx) {
  __shared__ u16 Kl[2][4096];
  __shared__ u16 Vl[2][4096];
  __shared__ u16 Pl[4][16 * 40];
  const int t = threadIdx.x, w = t >> 6, l = t & 63, lr = l & 15, lk = l >> 4;
  const int lin = blockIdx.x;
  const int xcd = lin & 7, idx = lin >> 3;
  const int bh = xcd * 4 + (idx >> 5);
  const int chunk = idx & 31;
  const int b = bh >> 4, h = bh & 15;
  const int srow = chunk * 64 + w * 16;
  const u16* Qb = Q + ((size_t)bh * S_ + srow) * D_;
  bf16x8 qf[4];
#pragma unroll
  for (int kc = 0; kc < 4; ++kc)
    qf[kc] = *(const bf16x8*)&Qb[lr * D_ + kc * 32 + lk * 8];
  f32x4 oacc[8] = {};
  float den[4] = {};
  const u16* Kb = Kq + (size_t)bh * M_ * D_;
  const u16* Vb = Vt + (size_t)bh * D_ * M_;
  const float invn = 0.08838834764831845f;
  u32 ksrc[2], vsrc[2];
#pragma unroll
  for (int i = 0; i < 2; ++i) {
    const int kidx = i * 256 + t;
    const int kr = kidx >> 4, kc_ = (kidx & 15) ^ (kr & 7);
    ksrc[i] = (u32)kr * D_ + (u32)kc_ * 8;
    const int vidx = i * 256 + t;
    const int vd = vidx >> 2, vc = (vidx & 3) ^ ((vd >> 1) & 3);
    vsrc[i] = (u32)vd * M_ + (u32)vc * 8;
  }
  const int wdst = w * 64 * 8;
  u32 mrow[4];
#pragma unroll
  for (int j2 = 0; j2 < 4; ++j2)
    mrow[j2] = ((u32)b * S_ + (u32)(srow + lk * 4 + j2)) * 64u;

#define STG(buf, m0) do {                                                                              \
    _Pragma("unroll")                                                                                  \
    for (int i = 0; i < 2; ++i) {                                                                      \
      __builtin_amdgcn_global_load_lds(GLBP(Kb + (size_t)(m0) * D_ + ksrc[i]),                         \
                                       LDSP(&Kl[buf][i * 2048 + wdst]), 16, 0, 0);                     \
      __builtin_amdgcn_global_load_lds(GLBP(Vb + (size_t)(m0) + vsrc[i]),                              \
                                       LDSP(&Vl[buf][i * 2048 + wdst]), 16, 0, 0);                     \
    }                                                                                                  \
  } while (0)

  STG(0, 0);
  asm volatile("s_waitcnt vmcnt(0)" ::: "memory");
  __builtin_amdgcn_s_barrier();
  int cur = 0;

  for (int t64 = 0; t64 < M_ / 32; ++t64) {
    const int m0 = t64 * 32;
    if (t64 + 1 < M_ / 32) STG(cur ^ 1, m0 + 32);
    u32 mw[4];
#pragma unroll
    for (int j2 = 0; j2 < 4; ++j2) mw[j2] = BM32[mrow[j2] + t64];
    f32x4 sc[2] = {};
#pragma unroll
    for (int mf = 0; mf < 2; ++mf) {
      const int r = mf * 16 + lr;
#pragma unroll
      for (int kc = 0; kc < 4; ++kc) {
        const int cc = ((kc * 4 + lk) ^ (r & 7));
        bf16x8 kfv = *(const bf16x8*)&Kl[cur][r * 128 + cc * 8];
        sc[mf] = __builtin_amdgcn_mfma_f32_16x16x32_bf16(qf[kc], kfv, sc[mf], 0, 0, 0);
      }
    }
#pragma unroll
    for (int j2 = 0; j2 < 4; ++j2) {
      const int rloc = lk * 4 + j2;
#pragma unroll
      for (int mf = 0; mf < 2; ++mf) {
        float p = __expf(sc[mf][j2] * invn);
        p = ((mw[j2] >> (mf * 16 + lr)) & 1u) ? p : 0.0f;
        den[j2] += p;
        Pl[w][rloc * 40 + mf * 16 + lr] = f2b(p);
      }
    }
    asm volatile("s_waitcnt lgkmcnt(0)" ::: "memory");
    __builtin_amdgcn_sched_barrier(0);
    bf16x8 pa = *(const bf16x8*)&Pl[w][lr * 40 + lk * 8];
#pragma unroll
    for (int nf = 0; nf < 8; ++nf) {
      const int d = nf * 16 + lr;
      const int cc = lk ^ ((d >> 1) & 3);
      bf16x8 vfv = *(const bf16x8*)&Vl[cur][d * 32 + cc * 8];
      oacc[nf] = __builtin_amdgcn_mfma_f32_16x16x32_bf16(pa, vfv, oacc[nf], 0, 0, 0);
    }
    asm volatile("s_waitcnt vmcnt(0)" ::: "memory");
    __builtin_amdgcn_s_barrier();
    cur ^= 1;
  }
#undef STG
#pragma unroll
  for (int j2 = 0; j2 < 4; ++j2) {
    float d = den[j2];
    d += __shfl_xor(d, 1); d += __shfl_xor(d, 2); d += __shfl_xor(d, 4); d += __shfl_xor(d, 8);
    den[j2] = 1.0f / fmaxf(d, 1e-20f);
  }
#pragma unroll
  for (int nf = 0; nf < 8; ++nf)
#pragma unroll
    for (int j2 = 0; j2 < 4; ++j2) {
      const int s = srow + lk * 4 + j2;
      const int dd = nf * 16 + lr;
      ctx[((size_t)s * B_ + b) * H_ + h * D_ + dd] = f2b(oacc[nf][j2] * den[j2]);
    }
}

// ------------------------------------------------------------------- host
extern "C" void kernel_launch(void* const* d_in, const int* in_sizes, int n_in,
                              void* d_out, int out_size, void* d_ws, size_t ws_size,
                              hipStream_t stream) {
  (void)in_sizes; (void)n_in; (void)out_size; (void)ws_size;
  char* ws = (char*)d_ws;
  u16* WT     = (u16*)(ws + 0);
  void* MID   = (void*)(ws + 33554432);
  float* XF   = (float*)(ws + 100663296);
  u16* HB     = (u16*)(ws + 134217728);
  u16* MEMB   = (u16*)(ws + 150994944);
  u16* QB     = (u16*)(ws + 167772160);
  u16* KB     = (u16*)(ws + 184549376);
  u16* VTB    = (u16*)(ws + 201326592);
  u64* BMB    = (u64*)(ws + 218103808);
  float* SM   = (float*)(ws + 234881024);
  int* FLAGS  = (int*)(ws + 235044864);

  float* Bias1  = SM + 0;
  float* Bias1o = SM + 8192;
  float* BiasQ  = SM + 10240;
  float* BiasKV = SM + 12288;
  float* BiasD  = SM + 16384;
  float* Bias2  = SM + 18432;
  float* Bias2o = SM + 26624;
  float* G1v = SM + 28672; float* B1v = SM + 30720;
  float* G2v = SM + 32768; float* B2v = SM + 34816;
  float* G3v = SM + 36864; float* B3v = SM + 38912;

  detect_kinds<<<1, 64, 0, stream>>>((const u32*)d_in[0], (const u32*)d_in[2], FLAGS);

  cvt_all<<<160, 256, 0, stream>>>(d_in[10], d_in[12], d_in[14], d_in[16], d_in[18],
                                   d_in[20], d_in[22], d_in[3], d_in[4], d_in[5],
                                   d_in[6], d_in[7], d_in[8], FLAGS, SM);

  mask_bits<<<(B_ * S_ * M_) / 256, 256, 0, stream>>>(d_in[2], FLAGS, BMB);
  cast_in_bf16<<<(MB_ * H_ / 8) / 256, 256, 0, stream>>>(d_in[1], FLAGS, MEMB, MB_ * H_ / 8);

  dim3 blk(256);
  dim3 blk5(512);
  // ---- mlp1
  layernorm_k<1><<<SB_, blk, 0, stream>>>(d_in[0], FLAGS, G1v, B1v, HB);
  transpose_cast<<<dim3(FF_ / 64, H_ / 64), blk, 0, stream>>>(d_in[9], FLAGS, WT, H_, FF_);
  gemm8p<256, 1, 0, 0, 1, 0><<<dim3(FF_ / 256, SB_ / 256), blk5, 0, stream>>>(HB, WT, Bias1, nullptr, nullptr, (u16*)MID, FLAGS, SB_, FF_, H_);
  transpose_cast<<<dim3(H_ / 64, FF_ / 64), blk, 0, stream>>>(d_in[11], FLAGS, WT, FF_, H_);
  gemm8p<128, 0, 0, 1, 0, 0><<<dim3(H_ / 128, SB_ / 256), blk5, 0, stream>>>((u16*)MID, WT, Bias1o, nullptr, XF, nullptr, FLAGS, SB_, H_, FF_);

  // ---- memory attention
  layernorm_k<0><<<SB_, blk, 0, stream>>>(XF, FLAGS, G2v, B2v, HB);
  transpose_cast<<<dim3(H_ / 64, H_ / 64), blk, 0, stream>>>(d_in[13], FLAGS, WT, H_, H_);
  gemm8p<128, 0, 0, 1, 0, 0><<<dim3(H_ / 128, SB_ / 256), blk5, 0, stream>>>(HB, WT, BiasQ, nullptr, MID, nullptr, FLAGS, SB_, H_, H_);
  l2_q<<<(SB_ * NH_) / 64, blk, 0, stream>>>((const float*)MID, QB);
  transpose_cast<<<dim3(2 * H_ / 64, H_ / 64), blk, 0, stream>>>(d_in[15], FLAGS, WT, H_, 2 * H_);
  gemm8p<256, 0, 0, 1, 0, 0><<<dim3(2 * H_ / 256, MB_ / 256), blk5, 0, stream>>>(MEMB, WT, BiasKV, nullptr, MID, nullptr, FLAGS, MB_, 2 * H_, H_);
  l2_kv<<<B_ * NH_ * (M_ / 64), blk, 0, stream>>>((const float*)MID, KB, VTB);
  attn_k<<<1024, blk, 0, stream>>>(QB, KB, VTB, (const u32*)BMB, MEMB);
  transpose_cast<<<dim3(H_ / 64, H_ / 64), blk, 0, stream>>>(d_in[17], FLAGS, WT, H_, H_);
  gemm8p<128, 0, 1, 1, 0, 0><<<dim3(H_ / 128, SB_ / 256), blk5, 0, stream>>>(MEMB, WT, BiasD, XF, XF, nullptr, FLAGS, SB_, H_, H_);

  // ---- mlp2
  layernorm_k<0><<<SB_, blk, 0, stream>>>(XF, FLAGS, G3v, B3v, HB);
  transpose_cast<<<dim3(FF_ / 64, H_ / 64), blk, 0, stream>>>(d_in[19], FLAGS, WT, H_, FF_);
  gemm8p<256, 1, 0, 0, 1, 0><<<dim3(FF_ / 256, SB_ / 256), blk5, 0, stream>>>(HB, WT, Bias2, nullptr, nullptr, (u16*)MID, FLAGS, SB_, FF_, H_);
  transpose_cast<<<dim3(H_ / 64, FF_ / 64), blk, 0, stream>>>(d_in[21], FLAGS, WT, FF_, H_);
  gemm8p<128, 0, 1, 1, 0, 1><<<dim3(H_ / 128, SB_ / 256), blk5, 0, stream>>>((u16*)MID, WT, Bias2o, XF, d_out, nullptr, FLAGS, SB_, H_, FF_);
}

// Round 10
// 1151.818 us; speedup vs baseline: 1.2674x; 1.0858x over previous
//
#include <hip/hip_runtime.h>
#include <stdint.h>
#include <stddef.h>

typedef __attribute__((ext_vector_type(8))) short bf16x8;
typedef __attribute__((ext_vector_type(4))) float f32x4;
typedef unsigned short u16;
typedef unsigned int u32;
typedef unsigned long long u64;

static constexpr int S_ = 2048, B_ = 2, H_ = 2048, NH_ = 16, D_ = 128, M_ = 2048, FF_ = 8192;
static constexpr int SB_ = S_ * B_;
static constexpr int MB_ = M_ * B_;

__device__ __forceinline__ float b2f(u16 b) {
  union { u32 u; float f; } v; v.u = ((u32)b) << 16; return v.f;
}
__device__ __forceinline__ u16 f2b(float f) {
  union { float f; u32 u; } v; v.f = f;
  u32 u = v.u;
  return (u16)((u + 0x7FFFu + ((u >> 16) & 1u)) >> 16);
}
__device__ __forceinline__ float geluf(float x) {
  float x3 = x * x * x;
  return 0.5f * x * (1.0f + tanhf(0.7978845608028654f * (x + 0.044715f * x3)));
}

#define LDSP(p) (reinterpret_cast<__attribute__((address_space(3))) uint32_t*>(reinterpret_cast<uintptr_t>(p)))
#define GLBP(p) (reinterpret_cast<const __attribute__((address_space(1))) uint32_t*>(reinterpret_cast<uintptr_t>(p)))

// ---------------------------------------------------------------- detectors
__global__ void detect_kinds(const u32* __restrict__ x0, const u32* __restrict__ mask, int* __restrict__ flags) {
  if (threadIdx.x == 0 && blockIdx.x == 0) {
    int cnt = 0;
    for (int i = 0; i < 256; ++i) {
      u32 e = (x0[i] >> 7) & 0xFFu;
      if (e >= 118u && e <= 130u) ++cnt;
    }
    flags[0] = (cnt >= 128) ? 0 : 1;
    int all01 = 1, allf = 1, allb = 1;
    for (int i = 0; i < 256; ++i) {
      u32 v = mask[i];
      if (v > 1u) all01 = 0;
      if (v != 0u && v != 0x3F800000u) allf = 0;
      u32 lo = v & 0xFFFFu, hi = v >> 16;
      if ((lo != 0u && lo != 0x3F80u) || (hi != 0u && hi != 0x3F80u)) allb = 0;
    }
    flags[1] = all01 ? 1 : (allf ? 3 : (allb ? 2 : 0));
  }
}

// mask -> packed bitmask: bit m = 1 iff UNMASKED
__global__ void mask_bits(const void* __restrict__ mraw, const int* __restrict__ flags, u64* __restrict__ bm) {
  int i = blockIdx.x * 256 + threadIdx.x;
  int kind = flags[1];
  int masked;
  if (kind == 1)      masked = ((const int*)mraw)[i] != 0;
  else if (kind == 3) masked = ((const float*)mraw)[i] != 0.0f;
  else if (kind == 2) masked = ((const u16*)mraw)[i] != 0;
  else                masked = ((const unsigned char*)mraw)[i] != 0;
  u64 vote = __ballot(masked == 0);
  if ((threadIdx.x & 63) == 0) bm[i >> 6] = vote;
}

// one launch for all 13 small f32 param conversions
__global__ void cvt_all(const void* s0, const void* s1, const void* s2, const void* s3,
                        const void* s4, const void* s5, const void* s6, const void* s7,
                        const void* s8, const void* s9, const void* s10, const void* s11,
                        const void* s12, const int* __restrict__ flags, float* __restrict__ SM) {
  const int i = blockIdx.x * 256 + threadIdx.x;
  if (i >= 40960) return;
  const void* src; int off;
  if (i < 8192)       { src = s0;  off = 0; }
  else if (i < 10240) { src = s1;  off = 8192; }
  else if (i < 12288) { src = s2;  off = 10240; }
  else if (i < 16384) { src = s3;  off = 12288; }
  else if (i < 18432) { src = s4;  off = 16384; }
  else if (i < 26624) { src = s5;  off = 18432; }
  else if (i < 28672) { src = s6;  off = 26624; }
  else if (i < 30720) { src = s7;  off = 28672; }
  else if (i < 32768) { src = s8;  off = 30720; }
  else if (i < 34816) { src = s9;  off = 32768; }
  else if (i < 36864) { src = s10; off = 34816; }
  else if (i < 38912) { src = s11; off = 36864; }
  else                { src = s12; off = 38912; }
  const int j = i - off;
  SM[i] = flags[0] ? ((const float*)src)[j] : b2f(((const u16*)src)[j]);
}

__global__ void cast_in_bf16(const void* __restrict__ src, const int* __restrict__ flags, u16* __restrict__ dst, int n8) {
  int i = blockIdx.x * 256 + threadIdx.x;
  if (i >= n8) return;
  if (flags[0]) {
    const float4* p = (const float4*)src;
    float4 a = p[i * 2], c = p[i * 2 + 1];
    bf16x8 o;
    o[0] = (short)f2b(a.x); o[1] = (short)f2b(a.y); o[2] = (short)f2b(a.z); o[3] = (short)f2b(a.w);
    o[4] = (short)f2b(c.x); o[5] = (short)f2b(c.y); o[6] = (short)f2b(c.z); o[7] = (short)f2b(c.w);
    *(bf16x8*)&dst[i * 8] = o;
  } else {
    *(bf16x8*)&dst[i * 8] = ((const bf16x8*)src)[i];
  }
}

// ------------------------------------------------------------ transpose+cast
__global__ __launch_bounds__(256) void transpose_cast(const void* __restrict__ in, const int* __restrict__ flags,
                                                      u16* __restrict__ out, int R, int C) {
  __shared__ u16 tile[64][65];
  const int isf = flags[0];
  const int tr = blockIdx.y * 64, tc = blockIdx.x * 64;
  const int tx = threadIdx.x & 63, ty = threadIdx.x >> 6;
  const float* inf = (const float*)in;
  const u16* inb = (const u16*)in;
#pragma unroll
  for (int i = 0; i < 16; ++i) {
    int r = ty * 16 + i;
    size_t idx = (size_t)(tr + r) * C + tc + tx;
    tile[r][tx] = isf ? f2b(inf[idx]) : inb[idx];
  }
  __syncthreads();
#pragma unroll
  for (int i = 0; i < 16; ++i) {
    int c = ty * 16 + i;
    out[(size_t)(tc + c) * R + tr + tx] = tile[tx][c];
  }
}

// ---------------------------------------------------------------- layernorm
template <int EXT>
__global__ __launch_bounds__(256) void layernorm_k(const void* __restrict__ xin, const int* __restrict__ flags,
                                                   const float* __restrict__ g, const float* __restrict__ bta,
                                                   u16* __restrict__ out) {
  const int row = blockIdx.x, t = threadIdx.x;
  float v[8];
  bool bfmode = EXT && (flags[0] == 0);
  if (bfmode) {
    const u16* xr = (const u16*)xin + (size_t)row * H_ + t * 8;
    bf16x8 a = *(const bf16x8*)xr;
#pragma unroll
    for (int j = 0; j < 8; ++j) v[j] = b2f((u16)a[j]);
  } else {
    const float* xr = (const float*)xin + (size_t)row * H_ + t * 8;
    float4 a = *(const float4*)xr, c = *(const float4*)(xr + 4);
    v[0] = a.x; v[1] = a.y; v[2] = a.z; v[3] = a.w;
    v[4] = c.x; v[5] = c.y; v[6] = c.z; v[7] = c.w;
  }
  float s1 = 0.f, s2 = 0.f;
#pragma unroll
  for (int j = 0; j < 8; ++j) { s1 += v[j]; s2 += v[j] * v[j]; }
#pragma unroll
  for (int off = 32; off > 0; off >>= 1) { s1 += __shfl_down(s1, off); s2 += __shfl_down(s2, off); }
  __shared__ float red[8];
  const int w = t >> 6;
  if ((t & 63) == 0) { red[w] = s1; red[4 + w] = s2; }
  __syncthreads();
  s1 = red[0] + red[1] + red[2] + red[3];
  s2 = red[4] + red[5] + red[6] + red[7];
  const float mean = s1 * (1.0f / H_);
  const float rstd = rsqrtf(s2 * (1.0f / H_) - mean * mean + 1e-5f);
  bf16x8 o;
#pragma unroll
  for (int j = 0; j < 8; ++j) {
    float y = (v[j] - mean) * rstd * g[t * 8 + j] + bta[t * 8 + j];
    o[j] = (short)f2b(y);
  }
  *(bf16x8*)(out + (size_t)row * H_ + t * 8) = o;
}

// ------------------------------------------------------------------- GEMM
// Read-ahead minimal-sync GEMM.  128x128 tile, 256 thr = 4 waves (2Mx2N,
// per-wave 64x64).  BK=64, 2-slot double buffer (64KB LDS -> 2 blocks/CU).
// Per slice: TWO kk-halves; the ds_reads for the NEXT half are issued BEFORE
// the current half's MFMA cluster (pinned by sched_barrier) so the LDS burst
// drains under MFMA; ONE s_barrier + one vmcnt(0) per slice (mid-slice),
// placed so stage(s+1) [issued at slice top] becomes block-visible before the
// cross-slice read-ahead.  Hazards: slot overwritten by STAGE(s+2) was last
// read in slice-s part 1, one barrier earlier -> safe.  Swizzle: 16B-chunk
// XOR (stored = logical ^ (row&7)), linear gload_lds dest + inverse-permuted
// global source (rule #21); measured conflict-free (r4/r8: SQ_LDS_BANK_CONFLICT=0).
template <int GELU, int RES, int WF, int WB, int ODYN>
__global__ __launch_bounds__(256, 2) void gemmra(const u16* __restrict__ A, const u16* __restrict__ Bt,
                                                 const float* __restrict__ bias, const float* __restrict__ res,
                                                 void* __restrict__ outF, u16* __restrict__ outB,
                                                 const int* __restrict__ flags, int Mr, int N, int K) {
  __shared__ u16 lds[32768];   // 64 KiB: slot{0,1} x (A 16KB + B 16KB)
  const int t = threadIdx.x;
  const int w = t >> 6, l = t & 63, lr = l & 15, lk = l >> 4;
  const int wr = w >> 1, wc = w & 1;
  // 2D XCD-chunked block mapping (each XCD: 8-wide x cy-tall sub-grid)
  const int gx = gridDim.x, gy = gridDim.y;
  const int orig = blockIdx.y * gx + blockIdx.x;
  const int nwg = gx * gy, per = nwg >> 3;
  int tm, tn;
  if ((gx & 7) == 0 && (per & 7) == 0) {
    const int xcd = orig & 7, p = orig >> 3;
    const int ncx = gx >> 3, cy = per >> 3;
    const int ccol = xcd % ncx, crow = xcd / ncx;
    const int px = p & 7, py = p >> 3;
    tn = (ccol * 8 + px) * 128;
    tm = (crow * cy + py) * 128;
  } else {
    tn = (orig % gx) * 128;
    tm = (orig / gx) * 128;
  }
  // staging source offsets (inverse-swizzled 16B chunks), 4 rounds per operand
  u32 aofs[4], bofs[4];
#pragma unroll
  for (int i = 0; i < 4; ++i) {
    const int idx = i * 256 + t;
    const int srow = idx >> 3, sc = idx & 7;
    const int lc = sc ^ (srow & 7);
    aofs[i] = (u32)(tm + srow) * (u32)K + (u32)lc * 8;
    bofs[i] = (u32)(tn + srow) * (u32)K + (u32)lc * 8;
  }
  const int wdst = w * 512;   // u16: wave's 1KB chunk within a 4KB round
  // ds_read offsets: row*64 + ((kk*4+lk)^(row&7))*8 ; row&7 == lr&7
  const int cso0 = ((0 + lk) ^ (lr & 7)) * 8;
  const int cso1 = ((4 + lk) ^ (lr & 7)) * 8;
  int arow[4], brow[4];
#pragma unroll
  for (int f = 0; f < 4; ++f) {
    arow[f] = (wr * 64 + f * 16 + lr) * 64;
    brow[f] = (wc * 64 + f * 16 + lr) * 64;
  }

  const int NS = K >> 6;
  f32x4 acc[4][4] = {};

#define STG(sl) do {                                                                                  \
    u16* Ad = lds + ((sl) & 1) * 16384;                                                               \
    u16* Bd = Ad + 8192;                                                                              \
    const u32 ko = (u32)(sl) * 64;                                                                    \
    _Pragma("unroll")                                                                                 \
    for (int i = 0; i < 4; ++i) {                                                                     \
      __builtin_amdgcn_global_load_lds(GLBP(A + aofs[i] + ko), LDSP(Ad + i * 2048 + wdst), 16, 0, 0); \
      __builtin_amdgcn_global_load_lds(GLBP(Bt + bofs[i] + ko), LDSP(Bd + i * 2048 + wdst), 16, 0, 0);\
    }                                                                                                 \
  } while (0)
#define RD(afX, bqX, sl, cso) do {                                                                    \
    const u16* As_ = lds + ((sl) & 1) * 16384;                                                        \
    const u16* Bs_ = As_ + 8192;                                                                      \
    _Pragma("unroll")                                                                                 \
    for (int f = 0; f < 4; ++f) {                                                                     \
      afX[f] = *(const bf16x8*)(As_ + arow[f] + (cso));                                               \
      bqX[f] = *(const bf16x8*)(Bs_ + brow[f] + (cso));                                               \
    }                                                                                                 \
  } while (0)
#define MM(afX, bqX)                                                                                  \
  _Pragma("unroll") for (int nf = 0; nf < 4; ++nf)                                                    \
  _Pragma("unroll") for (int mf = 0; mf < 4; ++mf)                                                    \
    acc[mf][nf] = __builtin_amdgcn_mfma_f32_16x16x32_bf16(afX[mf], bqX[nf], acc[mf][nf], 0, 0, 0);

  bf16x8 afA[4], bqA[4], afB[4], bqB[4];

  // prologue: stage slot0, make visible, preload (0,kk0)
  STG(0);
  asm volatile("s_waitcnt vmcnt(0)" ::: "memory");
  __builtin_amdgcn_s_barrier();
  RD(afA, bqA, 0, cso0);
  asm volatile("s_waitcnt lgkmcnt(0)" ::: "memory");
  __builtin_amdgcn_sched_barrier(0);

  for (int s = 0; s < NS; ++s) {
    // ---- part 1: issue reads (s,kk1) + stage s+1, THEN MFMA kk0 (overlap)
    if (s + 1 < NS) STG(s + 1);
    RD(afB, bqB, s, cso1);
    __builtin_amdgcn_sched_barrier(0);   // pin: reads/stage issue before MFMA
    __builtin_amdgcn_s_setprio(1);
    MM(afA, bqA);
    __builtin_amdgcn_s_setprio(0);
    asm volatile("s_waitcnt lgkmcnt(0)" ::: "memory");
    __builtin_amdgcn_sched_barrier(0);
    // ---- mid-slice: make stage(s+1) block-visible
    asm volatile("s_waitcnt vmcnt(0)" ::: "memory");
    __builtin_amdgcn_s_barrier();
    // ---- part 2: issue read-ahead (s+1,kk0), THEN MFMA kk1 (overlap)
    if (s + 1 < NS) RD(afA, bqA, s + 1, cso0);
    __builtin_amdgcn_sched_barrier(0);
    __builtin_amdgcn_s_setprio(1);
    MM(afB, bqB);
    __builtin_amdgcn_s_setprio(0);
    asm volatile("s_waitcnt lgkmcnt(0)" ::: "memory");
    __builtin_amdgcn_sched_barrier(0);
  }
#undef STG
#undef RD
#undef MM

  const int obf = ODYN ? (flags[0] ? 0 : 1) : 0;
  (void)Mr;
#pragma unroll
  for (int mf = 0; mf < 4; ++mf) {
#pragma unroll
    for (int nf = 0; nf < 4; ++nf) {
      const int col = tn + wc * 64 + nf * 16 + lr;
      const float bv = bias[col];
#pragma unroll
      for (int j = 0; j < 4; ++j) {
        const int rw = tm + wr * 64 + mf * 16 + lk * 4 + j;
        float vv = acc[mf][nf][j] + bv;
        if (RES) vv += res[(size_t)rw * N + col];
        if (GELU) vv = geluf(vv);
        if (WF) {
          if (ODYN && obf) ((u16*)outF)[(size_t)rw * N + col] = f2b(vv);
          else ((float*)outF)[(size_t)rw * N + col] = vv;
        }
        if (WB) outB[(size_t)rw * N + col] = f2b(vv);
      }
    }
  }
}

// --------------------------------------------------------------- l2 norms
__global__ __launch_bounds__(256) void l2_q(const float* __restrict__ qpre, u16* __restrict__ Q) {
  const int t = threadIdx.x;
  const int g = blockIdx.x * 64 + (t >> 2);
  const int lg = t & 3;
  const int h = g & (NH_ - 1), sb = g >> 4;
  const float* p = qpre + (size_t)sb * H_ + h * D_ + lg * 32;
  float vv[32];
  float ss = 0.f;
#pragma unroll
  for (int i = 0; i < 8; ++i) {
    float4 a = *(const float4*)&p[i * 4];
    vv[i * 4 + 0] = a.x; vv[i * 4 + 1] = a.y; vv[i * 4 + 2] = a.z; vv[i * 4 + 3] = a.w;
    ss += a.x * a.x + a.y * a.y + a.z * a.z + a.w * a.w;
  }
  ss += __shfl_xor(ss, 1); ss += __shfl_xor(ss, 2);
  const float sc = rsqrtf(ss + 1e-12f);
  const int s = sb >> 1, b = sb & 1;
  u16* o = Q + ((size_t)(b * NH_ + h) * S_ + s) * D_ + lg * 32;
#pragma unroll
  for (int i = 0; i < 4; ++i) {
    bf16x8 ov;
#pragma unroll
    for (int j = 0; j < 8; ++j) ov[j] = (short)f2b(vv[i * 8 + j] * sc);
    *(bf16x8*)&o[i * 8] = ov;
  }
}

__global__ __launch_bounds__(256) void l2_kv(const float* __restrict__ kvpre, u16* __restrict__ Kq, u16* __restrict__ Vt) {
  __shared__ u16 vtT[128][72];
  const int t = threadIdx.x;
  const int bid = blockIdx.x;
  const int mt = bid & 31, h = (bid >> 5) & 15, b = bid >> 9;
  const int lm = t >> 2, lg = t & 3;
  const int m = mt * 64 + lm;
  const size_t rowoff = (size_t)(m * B_ + b) * (2 * H_) + h * 256;
  float vv[32];
  { // K half
    const float* p = kvpre + rowoff + lg * 32;
    float ss = 0.f;
#pragma unroll
    for (int i = 0; i < 8; ++i) {
      float4 a = *(const float4*)&p[i * 4];
      vv[i * 4 + 0] = a.x; vv[i * 4 + 1] = a.y; vv[i * 4 + 2] = a.z; vv[i * 4 + 3] = a.w;
      ss += a.x * a.x + a.y * a.y + a.z * a.z + a.w * a.w;
    }
    ss += __shfl_xor(ss, 1); ss += __shfl_xor(ss, 2);
    const float sc = rsqrtf(ss + 1e-12f);
    u16* o = Kq + ((size_t)(b * NH_ + h) * M_ + m) * D_ + lg * 32;
#pragma unroll
    for (int i = 0; i < 4; ++i) {
      bf16x8 ov;
#pragma unroll
      for (int j = 0; j < 8; ++j) ov[j] = (short)f2b(vv[i * 8 + j] * sc);
      *(bf16x8*)&o[i * 8] = ov;
    }
  }
  { // V half -> LDS transposed
    const float* p = kvpre + rowoff + 128 + lg * 32;
    float ss = 0.f;
#pragma unroll
    for (int i = 0; i < 8; ++i) {
      float4 a = *(const float4*)&p[i * 4];
      vv[i * 4 + 0] = a.x; vv[i * 4 + 1] = a.y; vv[i * 4 + 2] = a.z; vv[i * 4 + 3] = a.w;
      ss += a.x * a.x + a.y * a.y + a.z * a.z + a.w * a.w;
    }
    ss += __shfl_xor(ss, 1); ss += __shfl_xor(ss, 2);
    const float sc = rsqrtf(ss + 1e-12f);
#pragma unroll
    for (int i = 0; i < 32; ++i) vtT[lg * 32 + i][lm] = f2b(vv[i] * sc);
  }
  __syncthreads();
  const int d = t >> 1, half = t & 1;
  u16* o = Vt + ((size_t)(b * NH_ + h) * D_ + d) * M_ + mt * 64 + half * 32;
#pragma unroll
  for (int i = 0; i < 4; ++i) {
    bf16x8 ov = *(const bf16x8*)&vtT[d][half * 32 + i * 8];
    *(bf16x8*)&o[i * 8] = ov;
  }
}

// -------------------------------------------------------------- attention
// unchanged from round 8 (verified; 130 us)
__global__ __launch_bounds__(256, 3) void attn_k(const u16* __restrict__ Q, const u16* __restrict__ Kq,
                                                 const u16* __restrict__ Vt, const u32* __restrict__ BM32,
                                                 u16* __restrict__ ctx) {
  __shared__ u16 Kl[2][4096];
  __shared__ u16 Vl[2][4096];
  __shared__ u16 Pl[4][16 * 40];
  const int t = threadIdx.x, w = t >> 6, l = t & 63, lr = l & 15, lk = l >> 4;
  const int lin = blockIdx.x;
  const int xcd = lin & 7, idx = lin >> 3;
  const int bh = xcd * 4 + (idx >> 5);
  const int chunk = idx & 31;
  const int b = bh >> 4, h = bh & 15;
  const int srow = chunk * 64 + w * 16;
  const u16* Qb = Q + ((size_t)bh * S_ + srow) * D_;
  bf16x8 qf[4];
#pragma unroll
  for (int kc = 0; kc < 4; ++kc)
    qf[kc] = *(const bf16x8*)&Qb[lr * D_ + kc * 32 + lk * 8];
  f32x4 oacc[8] = {};
  float den[4] = {};
  const u16* Kb = Kq + (size_t)bh * M_ * D_;
  const u16* Vb = Vt + (size_t)bh * D_ * M_;
  const float invn = 0.08838834764831845f;
  u32 ksrc[2], vsrc[2];
#pragma unroll
  for (int i = 0; i < 2; ++i) {
    const int kidx = i * 256 + t;
    const int kr = kidx >> 4, kc_ = (kidx & 15) ^ (kr & 7);
    ksrc[i] = (u32)kr * D_ + (u32)kc_ * 8;
    const int vidx = i * 256 + t;
    const int vd = vidx >> 2, vc = (vidx & 3) ^ ((vd >> 1) & 3);
    vsrc[i] = (u32)vd * M_ + (u32)vc * 8;
  }
  const int wdst = w * 64 * 8;
  u32 mrow[4];
#pragma unroll
  for (int j2 = 0; j2 < 4; ++j2)
    mrow[j2] = ((u32)b * S_ + (u32)(srow + lk * 4 + j2)) * 64u;

#define STG(buf, m0) do {                                                                              \
    _Pragma("unroll")                                                                                  \
    for (int i = 0; i < 2; ++i) {                                                                      \
      __builtin_amdgcn_global_load_lds(GLBP(Kb + (size_t)(m0) * D_ + ksrc[i]),                         \
                                       LDSP(&Kl[buf][i * 2048 + wdst]), 16, 0, 0);                     \
      __builtin_amdgcn_global_load_lds(GLBP(Vb + (size_t)(m0) + vsrc[i]),                              \
                                       LDSP(&Vl[buf][i * 2048 + wdst]), 16, 0, 0);                     \
    }                                                                                                  \
  } while (0)

  STG(0, 0);
  asm volatile("s_waitcnt vmcnt(0)" ::: "memory");
  __builtin_amdgcn_s_barrier();
  int cur = 0;

  for (int t64 = 0; t64 < M_ / 32; ++t64) {
    const int m0 = t64 * 32;
    if (t64 + 1 < M_ / 32) STG(cur ^ 1, m0 + 32);
    u32 mw[4];
#pragma unroll
    for (int j2 = 0; j2 < 4; ++j2) mw[j2] = BM32[mrow[j2] + t64];
    f32x4 sc[2] = {};
#pragma unroll
    for (int mf = 0; mf < 2; ++mf) {
      const int r = mf * 16 + lr;
#pragma unroll
      for (int kc = 0; kc < 4; ++kc) {
        const int cc = ((kc * 4 + lk) ^ (r & 7));
        bf16x8 kfv = *(const bf16x8*)&Kl[cur][r * 128 + cc * 8];
        sc[mf] = __builtin_amdgcn_mfma_f32_16x16x32_bf16(qf[kc], kfv, sc[mf], 0, 0, 0);
      }
    }
#pragma unroll
    for (int j2 = 0; j2 < 4; ++j2) {
      const int rloc = lk * 4 + j2;
#pragma unroll
      for (int mf = 0; mf < 2; ++mf) {
        float p = __expf(sc[mf][j2] * invn);
        p = ((mw[j2] >> (mf * 16 + lr)) & 1u) ? p : 0.0f;
        den[j2] += p;
        Pl[w][rloc * 40 + mf * 16 + lr] = f2b(p);
      }
    }
    asm volatile("s_waitcnt lgkmcnt(0)" ::: "memory");
    __builtin_amdgcn_sched_barrier(0);
    bf16x8 pa = *(const bf16x8*)&Pl[w][lr * 40 + lk * 8];
#pragma unroll
    for (int nf = 0; nf < 8; ++nf) {
      const int d = nf * 16 + lr;
      const int cc = lk ^ ((d >> 1) & 3);
      bf16x8 vfv = *(const bf16x8*)&Vl[cur][d * 32 + cc * 8];
      oacc[nf] = __builtin_amdgcn_mfma_f32_16x16x32_bf16(pa, vfv, oacc[nf], 0, 0, 0);
    }
    asm volatile("s_waitcnt vmcnt(0)" ::: "memory");
    __builtin_amdgcn_s_barrier();
    cur ^= 1;
  }
#undef STG
#pragma unroll
  for (int j2 = 0; j2 < 4; ++j2) {
    float d = den[j2];
    d += __shfl_xor(d, 1); d += __shfl_xor(d, 2); d += __shfl_xor(d, 4); d += __shfl_xor(d, 8);
    den[j2] = 1.0f / fmaxf(d, 1e-20f);
  }
#pragma unroll
  for (int nf = 0; nf < 8; ++nf)
#pragma unroll
    for (int j2 = 0; j2 < 4; ++j2) {
      const int s = srow + lk * 4 + j2;
      const int dd = nf * 16 + lr;
      ctx[((size_t)s * B_ + b) * H_ + h * D_ + dd] = f2b(oacc[nf][j2] * den[j2]);
    }
}

// ------------------------------------------------------------------- host
extern "C" void kernel_launch(void* const* d_in, const int* in_sizes, int n_in,
                              void* d_out, int out_size, void* d_ws, size_t ws_size,
                              hipStream_t stream) {
  (void)in_sizes; (void)n_in; (void)out_size; (void)ws_size;
  char* ws = (char*)d_ws;
  u16* WT     = (u16*)(ws + 0);
  void* MID   = (void*)(ws + 33554432);
  float* XF   = (float*)(ws + 100663296);
  u16* HB     = (u16*)(ws + 134217728);
  u16* MEMB   = (u16*)(ws + 150994944);
  u16* QB     = (u16*)(ws + 167772160);
  u16* KB     = (u16*)(ws + 184549376);
  u16* VTB    = (u16*)(ws + 201326592);
  u64* BMB    = (u64*)(ws + 218103808);
  float* SM   = (float*)(ws + 234881024);
  int* FLAGS  = (int*)(ws + 235044864);

  float* Bias1  = SM + 0;
  float* Bias1o = SM + 8192;
  float* BiasQ  = SM + 10240;
  float* BiasKV = SM + 12288;
  float* BiasD  = SM + 16384;
  float* Bias2  = SM + 18432;
  float* Bias2o = SM + 26624;
  float* G1v = SM + 28672; float* B1v = SM + 30720;
  float* G2v = SM + 32768; float* B2v = SM + 34816;
  float* G3v = SM + 36864; float* B3v = SM + 38912;

  detect_kinds<<<1, 64, 0, stream>>>((const u32*)d_in[0], (const u32*)d_in[2], FLAGS);

  cvt_all<<<160, 256, 0, stream>>>(d_in[10], d_in[12], d_in[14], d_in[16], d_in[18],
                                   d_in[20], d_in[22], d_in[3], d_in[4], d_in[5],
                                   d_in[6], d_in[7], d_in[8], FLAGS, SM);

  mask_bits<<<(B_ * S_ * M_) / 256, 256, 0, stream>>>(d_in[2], FLAGS, BMB);
  cast_in_bf16<<<(MB_ * H_ / 8) / 256, 256, 0, stream>>>(d_in[1], FLAGS, MEMB, MB_ * H_ / 8);

  dim3 blk(256);
  // ---- mlp1
  layernorm_k<1><<<SB_, blk, 0, stream>>>(d_in[0], FLAGS, G1v, B1v, HB);
  transpose_cast<<<dim3(FF_ / 64, H_ / 64), blk, 0, stream>>>(d_in[9], FLAGS, WT, H_, FF_);
  gemmra<1, 0, 0, 1, 0><<<dim3(FF_ / 128, SB_ / 128), blk, 0, stream>>>(HB, WT, Bias1, nullptr, nullptr, (u16*)MID, FLAGS, SB_, FF_, H_);
  transpose_cast<<<dim3(H_ / 64, FF_ / 64), blk, 0, stream>>>(d_in[11], FLAGS, WT, FF_, H_);
  gemmra<0, 0, 1, 0, 0><<<dim3(H_ / 128, SB_ / 128), blk, 0, stream>>>((u16*)MID, WT, Bias1o, nullptr, XF, nullptr, FLAGS, SB_, H_, FF_);

  // ---- memory attention
  layernorm_k<0><<<SB_, blk, 0, stream>>>(XF, FLAGS, G2v, B2v, HB);
  transpose_cast<<<dim3(H_ / 64, H_ / 64), blk, 0, stream>>>(d_in[13], FLAGS, WT, H_, H_);
  gemmra<0, 0, 1, 0, 0><<<dim3(H_ / 128, SB_ / 128), blk, 0, stream>>>(HB, WT, BiasQ, nullptr, MID, nullptr, FLAGS, SB_, H_, H_);
  l2_q<<<(SB_ * NH_) / 64, blk, 0, stream>>>((const float*)MID, QB);
  transpose_cast<<<dim3(2 * H_ / 64, H_ / 64), blk, 0, stream>>>(d_in[15], FLAGS, WT, H_, 2 * H_);
  gemmra<0, 0, 1, 0, 0><<<dim3(2 * H_ / 128, MB_ / 128), blk, 0, stream>>>(MEMB, WT, BiasKV, nullptr, MID, nullptr, FLAGS, MB_, 2 * H_, H_);
  l2_kv<<<B_ * NH_ * (M_ / 64), blk, 0, stream>>>((const float*)MID, KB, VTB);
  attn_k<<<1024, blk, 0, stream>>>(QB, KB, VTB, (const u32*)BMB, MEMB);
  transpose_cast<<<dim3(H_ / 64, H_ / 64), blk, 0, stream>>>(d_in[17], FLAGS, WT, H_, H_);
  gemmra<0, 1, 1, 0, 0><<<dim3(H_ / 128, SB_ / 128), blk, 0, stream>>>(MEMB, WT, BiasD, XF, XF, nullptr, FLAGS, SB_, H_, H_);

  // ---- mlp2
  layernorm_k<0><<<SB_, blk, 0, stream>>>(XF, FLAGS, G3v, B3v, HB);
  transpose_cast<<<dim3(FF_ / 64, H_ / 64), blk, 0, stream>>>(d_in[19], FLAGS, WT, H_, FF_);
  gemmra<1, 0, 0, 1, 0><<<dim3(FF_ / 128, SB_ / 128), blk, 0, stream>>>(HB, WT, Bias2, nullptr, nullptr, (u16*)MID, FLAGS, SB_, FF_, H_);
  transpose_cast<<<dim3(H_ / 64, FF_ / 64), blk, 0, stream>>>(d_in[21], FLAGS, WT, FF_, H_);
  gemmra<0, 1, 1, 0, 1><<<dim3(H_ / 128, SB_ / 128), blk, 0, stream>>>((u16*)MID, WT, Bias2o, XF, d_out, nullptr, FLAGS, SB_, H_, FF_);
}